// Round 5
// baseline (11129.099 us; speedup 1.0000x reference)
//
#include <hip/hip_runtime.h>
#include <math.h>

#define NGRAPH 512

static inline unsigned grid_for(size_t n, int block = 256) {
    return (unsigned)((n + block - 1) / block);
}

__global__ void fill_kernel(float* __restrict__ p, float v, size_t n) {
    size_t i = blockIdx.x * (size_t)blockDim.x + threadIdx.x;
    if (i < n) p[i] = v;
}

__global__ void deg_kernel(const int* __restrict__ col, int E, float* __restrict__ deg) {
    size_t i = blockIdx.x * (size_t)blockDim.x + threadIdx.x;
    if (i < (size_t)E) atomicAdd(&deg[col[i]], 1.0f);
}

__global__ void dinv_kernel(float* __restrict__ d, int n) {
    size_t i = blockIdx.x * (size_t)blockDim.x + threadIdx.x;
    if (i < (size_t)n) d[i] = 1.0f / sqrtf(fmaxf(d[i], 1e-12f));
}

__global__ void coef_kernel(const int* __restrict__ row, const int* __restrict__ col,
                            const float* __restrict__ attr, const float* __restrict__ dinv,
                            float* __restrict__ coef, int E) {
    size_t i = blockIdx.x * (size_t)blockDim.x + threadIdx.x;
    if (i < (size_t)E) coef[i] = dinv[row[i]] * attr[i] * dinv[col[i]];
}

// Tiled GEMM: C[m][coff+n] = act(act_in(A[m][:]) @ W[:][n] + bias[n])
// optional fused self-loop: AGG[m][n] = dinv[m]^2 * C_val
// NOTE: SELF may only be used when AGG does NOT alias A (race otherwise).
template <int BM, int BN, int BK, int TM, int TN,
          bool RELU_IN, bool RELU_OUT, bool BIAS, bool SELF>
__global__ __launch_bounds__(256) void tgemm(
        const float* __restrict__ A, const float* __restrict__ W,
        const float* __restrict__ bias, float* __restrict__ C,
        float* __restrict__ AGG, const float* __restrict__ dinv,
        int M, int K, int N, int ldc, int coff) {
    const int tid = threadIdx.x;
    const int nthread_n = BN / TN;            // threads along n
    const int tx = tid % nthread_n;
    const int ty = tid / nthread_n;
    const int m0 = blockIdx.y * BM;
    const int n0 = blockIdx.x * BN;

    __shared__ float As[BK][BM + 4];          // transposed A tile
    __shared__ float Ws[BK][BN];

    float acc[TM][TN];
#pragma unroll
    for (int i = 0; i < TM; ++i)
#pragma unroll
        for (int j = 0; j < TN; ++j) acc[i][j] = 0.0f;

    for (int k0 = 0; k0 < K; k0 += BK) {
        __syncthreads();
        // load A tile (BM x BK), store transposed
        for (int idx = tid; idx < BM * BK; idx += 256) {
            int k = idx % BK;
            int m = idx / BK;
            float v = 0.0f;
            int gm = m0 + m, gk = k0 + k;
            if (gm < M && gk < K) {
                v = A[(size_t)gm * K + gk];
                if (RELU_IN) v = fmaxf(v, 0.0f);
            }
            As[k][m] = v;
        }
        // load W tile (BK x BN)
        for (int idx = tid; idx < BK * BN; idx += 256) {
            int n = idx % BN;
            int k = idx / BN;
            float v = 0.0f;
            int gk = k0 + k, gn = n0 + n;
            if (gk < K && gn < N) v = W[(size_t)gk * N + gn];
            Ws[k][n] = v;
        }
        __syncthreads();
#pragma unroll
        for (int kk = 0; kk < BK; ++kk) {
            float a[TM], b[TN];
#pragma unroll
            for (int i = 0; i < TM; ++i) a[i] = As[kk][ty * TM + i];
#pragma unroll
            for (int j = 0; j < TN; ++j) b[j] = Ws[kk][tx * TN + j];
#pragma unroll
            for (int i = 0; i < TM; ++i)
#pragma unroll
                for (int j = 0; j < TN; ++j) acc[i][j] = fmaf(a[i], b[j], acc[i][j]);
        }
    }

#pragma unroll
    for (int i = 0; i < TM; ++i) {
        int gm = m0 + ty * TM + i;
        if (gm >= M) continue;
        float s2 = 0.0f;
        if (SELF) {
            float s = dinv[gm];
            s2 = s * s;
        }
#pragma unroll
        for (int j = 0; j < TN; ++j) {
            int gn = n0 + tx * TN + j;
            if (gn >= N) continue;
            float v = acc[i][j];
            if (BIAS) v += bias[gn];
            if (RELU_OUT) v = fmaxf(v, 0.0f);
            C[(size_t)gm * ldc + coff + gn] = v;
            if (SELF) AGG[(size_t)gm * N + gn] = v * s2;
        }
    }
}

// AGG[n][f..f+V-1] = dinv[n]^2 * H[n][f..f+V-1]  (runs AFTER the GEMM kernel retires)
template <int V>
__global__ void self_init_vec(const float* __restrict__ H, const float* __restrict__ dinv,
                              float* __restrict__ AGG, int N, int F) {
    size_t idx = blockIdx.x * (size_t)blockDim.x + threadIdx.x;
    const int FV = F / V;
    if (idx >= (size_t)N * FV) return;
    size_t n = idx / FV;
    int f = (int)(idx % FV) * V;
    float s = dinv[n];
    float s2 = s * s;
    const float* hp = H + n * (size_t)F + f;
    float* ap = AGG + n * (size_t)F + f;
#pragma unroll
    for (int j = 0; j < V; ++j) ap[j] = hp[j] * s2;
}

// AGG[col[e]][f..f+V-1] += coef[e] * H[row[e]][f..f+V-1]
template <int V>
__global__ void scatter_vec(const int* __restrict__ row, const int* __restrict__ col,
                            const float* __restrict__ coef, const float* __restrict__ H,
                            float* __restrict__ AGG, int E, int F) {
    size_t idx = blockIdx.x * (size_t)blockDim.x + threadIdx.x;
    const int FV = F / V;
    if (idx >= (size_t)E * FV) return;
    size_t e = idx / FV;
    int f = (int)(idx % FV) * V;
    int r = row[e], c = col[e];
    float cf = coef[e];
    const float* hp = H + (size_t)r * F + f;
    float* ap = AGG + (size_t)c * F + f;
#pragma unroll
    for (int j = 0; j < V; ++j) atomicAdd(&ap[j], cf * hp[j]);
}

// sums[batch[n]][f..] += relu(X[n][f..]); cnt[batch[n]] += 1 (once per node)
template <int V>
__global__ void pool_sum_vec(const float* __restrict__ X, const int* __restrict__ batch,
                             float* __restrict__ sums, float* __restrict__ cnt, int N, int F) {
    size_t idx = blockIdx.x * (size_t)blockDim.x + threadIdx.x;
    const int FV = F / V;
    if (idx >= (size_t)N * FV) return;
    size_t n = idx / FV;
    int f = (int)(idx % FV) * V;
    int g = batch[n];
    const float* xp = X + n * (size_t)F + f;
    float* sp = sums + (size_t)g * F + f;
#pragma unroll
    for (int j = 0; j < V; ++j) atomicAdd(&sp[j], fmaxf(xp[j], 0.0f));
    if (f == 0) atomicAdd(&cnt[g], 1.0f);
}

__global__ void pool_div_kernel(float* __restrict__ sums, const float* __restrict__ cnt, int F) {
    size_t idx = blockIdx.x * (size_t)blockDim.x + threadIdx.x;
    if (idx >= (size_t)NGRAPH * F) return;
    sums[idx] /= fmaxf(cnt[idx / F], 1.0f);
}

// small thread-per-output GEMM (for N=64 layers)
template <bool RELU_OUT>
__global__ void mlp_gemm(const float* __restrict__ A, const float* __restrict__ W,
                         const float* __restrict__ b, float* __restrict__ C,
                         int K, int M, int ldc, int coff) {
    size_t idx = blockIdx.x * (size_t)blockDim.x + threadIdx.x;
    if (idx >= (size_t)NGRAPH * M) return;
    int m = (int)(idx % M);
    size_t g = idx / M;
    const float* ar = A + g * (size_t)K;
    float acc = b[m];
    for (int k = 0; k < K; ++k) acc = fmaf(ar[k], W[(size_t)k * M + m], acc);
    if (RELU_OUT) acc = fmaxf(acc, 0.0f);
    C[g * (size_t)ldc + coff + m] = acc;
}

__global__ void final_kernel(const float* __restrict__ A, const float* __restrict__ w,
                             const float* __restrict__ b, float* __restrict__ out, int K) {
    int g = blockIdx.x * blockDim.x + threadIdx.x;
    if (g >= NGRAPH) return;
    float acc = b[0];
    const float* ar = A + (size_t)g * K;
    for (int k = 0; k < K; ++k) acc = fmaf(ar[k], w[k], acc);
    out[g] = acc;
}

static inline dim3 tgrid(int M, int N, int BM, int BN) {
    return dim3((unsigned)((N + BN - 1) / BN), (unsigned)((M + BM - 1) / BM));
}

extern "C" void kernel_launch(void* const* d_in, const int* in_sizes, int n_in,
                              void* d_out, int out_size, void* d_ws, size_t ws_size,
                              hipStream_t stream) {
    const float* drug_x  = (const float*)d_in[0];
    const int*   d_ei    = (const int*)d_in[1];
    const float* d_ea    = (const float*)d_in[2];
    const int*   d_batch = (const int*)d_in[3];
    const float* prot_x  = (const float*)d_in[4];
    const int*   p_ei    = (const int*)d_in[5];
    const float* p_ea    = (const float*)d_in[6];
    const int*   p_batch = (const int*)d_in[7];
    const float* dW1 = (const float*)d_in[8];
    const float* dW2 = (const float*)d_in[9];
    const float* dW3 = (const float*)d_in[10];
    const float* dL1_w = (const float*)d_in[11];
    const float* dL1_b = (const float*)d_in[12];
    const float* dL2_w = (const float*)d_in[13];
    const float* dL2_b = (const float*)d_in[14];
    const float* pW1 = (const float*)d_in[15];
    const float* pW2 = (const float*)d_in[16];
    const float* pW3 = (const float*)d_in[17];
    const float* pL1_w = (const float*)d_in[18];
    const float* pL1_b = (const float*)d_in[19];
    const float* pL2_w = (const float*)d_in[20];
    const float* pL2_b = (const float*)d_in[21];
    const float* fW1 = (const float*)d_in[22];
    const float* fb1 = (const float*)d_in[23];
    const float* fW2 = (const float*)d_in[24];
    const float* fb2 = (const float*)d_in[25];
    const float* fW3 = (const float*)d_in[26];
    const float* fb3 = (const float*)d_in[27];
    float* out = (float*)d_out;

    const int Nd = in_sizes[0] / 78;
    const int Ed = in_sizes[1] / 2;
    const int Np = in_sizes[4] / 20;
    const int Ep = in_sizes[5] / 2;
    const int* d_row = d_ei;
    const int* d_col = d_ei + Ed;
    const int* p_row = p_ei;
    const int* p_col = p_ei + Ep;

    float* ws = (float*)d_ws;
    size_t off = 0;
    auto take = [&](size_t n) -> float* {
        float* p = ws + off;
        off += (n + 255) & ~(size_t)255;
        return p;
    };
    float* B1     = take((size_t)Nd * 312);  // gemm output H (reused for protein)
    float* B2     = take((size_t)Nd * 312);  // aggregate (reused for protein)
    float* dinv_d = take((size_t)Nd);
    float* dinv_p = take((size_t)Np);
    float* coef_d = take((size_t)Ed);
    float* coef_p = take((size_t)Ep);
    float* pool   = take((size_t)NGRAPH * 312);
    float* cnt    = take((size_t)NGRAPH);
    float* t1     = take((size_t)NGRAPH * 1024);
    float* Cbuf   = take((size_t)NGRAPH * 128);
    float* f2buf  = take((size_t)NGRAPH * 512);
    (void)ws_size;

    const int B = 256;

    // ---- degree / dinv / edge coefficients (shared across layers) ----
    fill_kernel<<<grid_for(Nd), B, 0, stream>>>(dinv_d, 1.0f, (size_t)Nd);
    deg_kernel<<<grid_for(Ed), B, 0, stream>>>(d_col, Ed, dinv_d);
    dinv_kernel<<<grid_for(Nd), B, 0, stream>>>(dinv_d, Nd);
    coef_kernel<<<grid_for(Ed), B, 0, stream>>>(d_row, d_col, d_ea, dinv_d, coef_d, Ed);

    fill_kernel<<<grid_for(Np), B, 0, stream>>>(dinv_p, 1.0f, (size_t)Np);
    deg_kernel<<<grid_for(Ep), B, 0, stream>>>(p_col, Ep, dinv_p);
    dinv_kernel<<<grid_for(Np), B, 0, stream>>>(dinv_p, Np);
    coef_kernel<<<grid_for(Ep), B, 0, stream>>>(p_row, p_col, p_ea, dinv_p, coef_p, Ep);

    // ---- drug GCN: 78 -> 78 -> 156 -> 312 ----
    // conv1: A = drug_x (no alias) -> SELF fused
    tgemm<128,128,8,8,8,false,false,false,true><<<tgrid(Nd,78,128,128), B, 0, stream>>>(
        drug_x, dW1, nullptr, B1, B2, dinv_d, Nd, 78, 78, 78, 0);
    scatter_vec<2><<<grid_for((size_t)Ed * 39), B, 0, stream>>>(d_row, d_col, coef_d, B1, B2, Ed, 78);

    // conv2: A = B2 aliases AGG -> separate self_init after GEMM
    tgemm<128,128,8,8,8,true,false,false,false><<<tgrid(Nd,156,128,128), B, 0, stream>>>(
        B2, dW2, nullptr, B1, nullptr, nullptr, Nd, 78, 156, 156, 0);
    self_init_vec<4><<<grid_for((size_t)Nd * 39), B, 0, stream>>>(B1, dinv_d, B2, Nd, 156);
    scatter_vec<4><<<grid_for((size_t)Ed * 39), B, 0, stream>>>(d_row, d_col, coef_d, B1, B2, Ed, 156);

    // conv3
    tgemm<128,128,8,8,8,true,false,false,false><<<tgrid(Nd,312,128,128), B, 0, stream>>>(
        B2, dW3, nullptr, B1, nullptr, nullptr, Nd, 156, 312, 312, 0);
    self_init_vec<4><<<grid_for((size_t)Nd * 78), B, 0, stream>>>(B1, dinv_d, B2, Nd, 312);
    scatter_vec<4><<<grid_for((size_t)Ed * 78), B, 0, stream>>>(d_row, d_col, coef_d, B1, B2, Ed, 312);

    fill_kernel<<<grid_for((size_t)NGRAPH * 312), B, 0, stream>>>(pool, 0.0f, (size_t)NGRAPH * 312);
    fill_kernel<<<grid_for(NGRAPH), B, 0, stream>>>(cnt, 0.0f, (size_t)NGRAPH);
    pool_sum_vec<4><<<grid_for((size_t)Nd * 78), B, 0, stream>>>(B2, d_batch, pool, cnt, Nd, 312);
    pool_div_kernel<<<grid_for((size_t)NGRAPH * 312), B, 0, stream>>>(pool, cnt, 312);

    tgemm<64,128,8,4,8,false,true,true,false><<<tgrid(NGRAPH,1024,64,128), B, 0, stream>>>(
        pool, dL1_w, dL1_b, t1, nullptr, nullptr, NGRAPH, 312, 1024, 1024, 0);
    mlp_gemm<true><<<grid_for((size_t)NGRAPH * 64), B, 0, stream>>>(t1, dL2_w, dL2_b, Cbuf, 1024, 64, 128, 0);

    // ---- protein GCN: 20 -> 20 -> 40 -> 80 ----
    tgemm<128,64,8,8,4,false,false,false,true><<<tgrid(Np,20,128,64), B, 0, stream>>>(
        prot_x, pW1, nullptr, B1, B2, dinv_p, Np, 20, 20, 20, 0);
    scatter_vec<4><<<grid_for((size_t)Ep * 5), B, 0, stream>>>(p_row, p_col, coef_p, B1, B2, Ep, 20);

    tgemm<128,64,8,8,4,true,false,false,false><<<tgrid(Np,40,128,64), B, 0, stream>>>(
        B2, pW2, nullptr, B1, nullptr, nullptr, Np, 20, 40, 40, 0);
    self_init_vec<4><<<grid_for((size_t)Np * 10), B, 0, stream>>>(B1, dinv_p, B2, Np, 40);
    scatter_vec<4><<<grid_for((size_t)Ep * 10), B, 0, stream>>>(p_row, p_col, coef_p, B1, B2, Ep, 40);

    tgemm<128,64,8,8,4,true,false,false,false><<<tgrid(Np,80,128,64), B, 0, stream>>>(
        B2, pW3, nullptr, B1, nullptr, nullptr, Np, 40, 80, 80, 0);
    self_init_vec<4><<<grid_for((size_t)Np * 20), B, 0, stream>>>(B1, dinv_p, B2, Np, 80);
    scatter_vec<4><<<grid_for((size_t)Ep * 20), B, 0, stream>>>(p_row, p_col, coef_p, B1, B2, Ep, 80);

    fill_kernel<<<grid_for((size_t)NGRAPH * 80), B, 0, stream>>>(pool, 0.0f, (size_t)NGRAPH * 80);
    fill_kernel<<<grid_for(NGRAPH), B, 0, stream>>>(cnt, 0.0f, (size_t)NGRAPH);
    pool_sum_vec<4><<<grid_for((size_t)Np * 20), B, 0, stream>>>(B2, p_batch, pool, cnt, Np, 80);
    pool_div_kernel<<<grid_for((size_t)NGRAPH * 80), B, 0, stream>>>(pool, cnt, 80);

    tgemm<64,128,8,4,8,false,true,true,false><<<tgrid(NGRAPH,1024,64,128), B, 0, stream>>>(
        pool, pL1_w, pL1_b, t1, nullptr, nullptr, NGRAPH, 80, 1024, 1024, 0);
    mlp_gemm<true><<<grid_for((size_t)NGRAPH * 64), B, 0, stream>>>(t1, pL2_w, pL2_b, Cbuf, 1024, 64, 128, 64);

    // ---- head: 128 -> 1024 -> 512 -> 1 ----
    tgemm<64,128,8,4,8,false,true,true,false><<<tgrid(NGRAPH,1024,64,128), B, 0, stream>>>(
        Cbuf, fW1, fb1, t1, nullptr, nullptr, NGRAPH, 128, 1024, 1024, 0);
    tgemm<64,128,8,4,8,false,true,true,false><<<tgrid(NGRAPH,512,64,128), B, 0, stream>>>(
        t1, fW2, fb2, f2buf, nullptr, nullptr, NGRAPH, 1024, 512, 512, 0);
    final_kernel<<<grid_for(NGRAPH), B, 0, stream>>>(f2buf, fW3, fb3, out, 512);
}

// Round 7
// 3200.542 us; speedup vs baseline: 3.4773x; 3.4773x over previous
//
#include <hip/hip_runtime.h>
#include <math.h>

#define NGRAPH 512

static inline unsigned grid_for(size_t n, int block = 256) {
    return (unsigned)((n + block - 1) / block);
}

__global__ void fill_i32(int* __restrict__ p, int v, size_t n) {
    size_t i = blockIdx.x * (size_t)blockDim.x + threadIdx.x;
    if (i < n) p[i] = v;
}

// histogram of destination indices
__global__ void hist_kernel(const int* __restrict__ col, int E, int* __restrict__ cnt) {
    size_t i = blockIdx.x * (size_t)blockDim.x + threadIdx.x;
    if (i < (size_t)E) atomicAdd(&cnt[col[i]], 1);
}

// dinv[n] = (cnt[n] + 1)^-0.5   (+1 = self loop)
__global__ void dinv_kernel(const int* __restrict__ cnt, float* __restrict__ d, int n) {
    size_t i = blockIdx.x * (size_t)blockDim.x + threadIdx.x;
    if (i < (size_t)n) d[i] = 1.0f / sqrtf((float)cnt[i] + 1.0f);
}

// ---- 3-pass exclusive scan over pos[] (in-place; n <= ~262k) ----
__global__ void scan_pass1(const int* __restrict__ in, int* __restrict__ bsum, int n) {
    __shared__ int sdata[256];
    int tid = threadIdx.x;
    int i = blockIdx.x * 256 + tid;
    int v = (i < n) ? in[i] : 0;
    sdata[tid] = v;
    __syncthreads();
    for (int s = 128; s > 0; s >>= 1) {
        if (tid < s) sdata[tid] += sdata[tid + s];
        __syncthreads();
    }
    if (tid == 0) bsum[blockIdx.x] = sdata[0];
}

__global__ void scan_pass2(int* __restrict__ bsum, int nb) {
    if (threadIdx.x == 0 && blockIdx.x == 0) {
        int acc = 0;
        for (int i = 0; i < nb; ++i) { int t = bsum[i]; bsum[i] = acc; acc += t; }
        bsum[nb] = acc;
    }
}

// in-place: pos[i] <- exclusive prefix (each block reads only its own segment first)
__global__ void scan_pass3(int* __restrict__ pos, const int* __restrict__ bsum, int n) {
    __shared__ int sdata[256];
    int tid = threadIdx.x;
    int i = blockIdx.x * 256 + tid;
    int v = (i < n) ? pos[i] : 0;
    sdata[tid] = v;
    __syncthreads();
    for (int ofs = 1; ofs < 256; ofs <<= 1) {
        int t = (tid >= ofs) ? sdata[tid - ofs] : 0;
        __syncthreads();
        sdata[tid] += t;
        __syncthreads();
    }
    if (i < n) pos[i] = sdata[tid] - v + bsum[blockIdx.x];
}

// CSR fill: slot = pos[col[e]]++; after this kernel pos[i] == inclusive end of node i
__global__ void csr_fill(const int* __restrict__ row, const int* __restrict__ col,
                         const float* __restrict__ attr, const float* __restrict__ dinv,
                         int* __restrict__ pos, int* __restrict__ rowp,
                         float* __restrict__ coefp, int E) {
    size_t i = blockIdx.x * (size_t)blockDim.x + threadIdx.x;
    if (i >= (size_t)E) return;
    int r = row[i], c = col[i];
    int slot = atomicAdd(&pos[c], 1);
    rowp[slot] = r;
    coefp[slot] = dinv[r] * attr[i] * dinv[c];
}

// Tiled GEMM: C[m][n] = act_out(act_in(A[m][:]) @ W[:][n] + bias[n])
template <int BM, int BN, int BK, int TM, int TN,
          bool RELU_IN, bool RELU_OUT, bool BIAS>
__global__ __launch_bounds__(256) void tgemm(
        const float* __restrict__ A, const float* __restrict__ W,
        const float* __restrict__ bias, float* __restrict__ C,
        int M, int K, int N, int ldc, int coff) {
    const int tid = threadIdx.x;
    const int nthread_n = BN / TN;
    const int tx = tid % nthread_n;
    const int ty = tid / nthread_n;
    const int m0 = blockIdx.y * BM;
    const int n0 = blockIdx.x * BN;

    __shared__ float As[BK][BM + 4];
    __shared__ float Ws[BK][BN];

    float acc[TM][TN];
#pragma unroll
    for (int i = 0; i < TM; ++i)
#pragma unroll
        for (int j = 0; j < TN; ++j) acc[i][j] = 0.0f;

    for (int k0 = 0; k0 < K; k0 += BK) {
        __syncthreads();
        for (int idx = tid; idx < BM * BK; idx += 256) {
            int k = idx % BK;
            int m = idx / BK;
            float v = 0.0f;
            int gm = m0 + m, gk = k0 + k;
            if (gm < M && gk < K) {
                v = A[(size_t)gm * K + gk];
                if (RELU_IN) v = fmaxf(v, 0.0f);
            }
            As[k][m] = v;
        }
        for (int idx = tid; idx < BK * BN; idx += 256) {
            int n = idx % BN;
            int k = idx / BN;
            float v = 0.0f;
            int gk = k0 + k, gn = n0 + n;
            if (gk < K && gn < N) v = W[(size_t)gk * N + gn];
            Ws[k][n] = v;
        }
        __syncthreads();
#pragma unroll
        for (int kk = 0; kk < BK; ++kk) {
            float a[TM], b[TN];
#pragma unroll
            for (int i = 0; i < TM; ++i) a[i] = As[kk][ty * TM + i];
#pragma unroll
            for (int j = 0; j < TN; ++j) b[j] = Ws[kk][tx * TN + j];
#pragma unroll
            for (int i = 0; i < TM; ++i)
#pragma unroll
                for (int j = 0; j < TN; ++j) acc[i][j] = fmaf(a[i], b[j], acc[i][j]);
        }
    }

#pragma unroll
    for (int i = 0; i < TM; ++i) {
        int gm = m0 + ty * TM + i;
        if (gm >= M) continue;
#pragma unroll
        for (int j = 0; j < TN; ++j) {
            int gn = n0 + tx * TN + j;
            if (gn >= N) continue;
            float v = acc[i][j];
            if (BIAS) v += bias[gn];
            if (RELU_OUT) v = fmaxf(v, 0.0f);
            C[(size_t)gm * ldc + coff + gn] = v;
        }
    }
}

template <int V> struct VT {};
template <> struct VT<2> { using T = float2; };
template <> struct VT<4> { using T = float4; };

// CSR gather-aggregate: AGG[n][:] = dinv[n]^2 * H[n][:] + sum_t coefp[t] * H[rowp[t]][:]
// Segment of node n is [ n? pos[n-1]:0 , pos[n] ).
template <int V, int LPG>
__global__ void gather_agg(const int* __restrict__ pos, const int* __restrict__ rowp,
                           const float* __restrict__ coefp, const float* __restrict__ H,
                           const float* __restrict__ dinv, float* __restrict__ AGG,
                           int N, int F) {
    using VecT = typename VT<V>::T;
    union U { VecT v; float a[V]; };
    const int gpb = 256 / LPG;
    int gid = blockIdx.x * gpb + threadIdx.x / LPG;
    int lane = threadIdx.x % LPG;
    if (gid >= N) return;
    int start = (gid == 0) ? 0 : pos[gid - 1];
    int end = pos[gid];
    float s = dinv[gid];
    float s2 = s * s;
    for (int f = lane * V; f < F; f += LPG * V) {
        U acc;
        acc.v = *reinterpret_cast<const VecT*>(H + (size_t)gid * F + f);
#pragma unroll
        for (int j = 0; j < V; ++j) acc.a[j] *= s2;
        for (int t = start; t < end; ++t) {
            int r = rowp[t];
            float cf = coefp[t];
            U h;
            h.v = *reinterpret_cast<const VecT*>(H + (size_t)r * F + f);
#pragma unroll
            for (int j = 0; j < V; ++j) acc.a[j] = fmaf(cf, h.a[j], acc.a[j]);
        }
        *reinterpret_cast<VecT*>(AGG + (size_t)gid * F + f) = acc.v;
    }
}

// segment mean-pool over sorted batch: out[g][f] = mean over nodes of relu(X[n][f])
__global__ void pool_mean(const float* __restrict__ X, const int* __restrict__ batch,
                          float* __restrict__ out, int N, int F) {
    int g = blockIdx.x;
    int lo = 0, hi = N;
    while (lo < hi) { int mid = (lo + hi) >> 1; if (batch[mid] < g) lo = mid + 1; else hi = mid; }
    int s0 = lo;
    hi = N;
    while (lo < hi) { int mid = (lo + hi) >> 1; if (batch[mid] < g + 1) lo = mid + 1; else hi = mid; }
    int s1 = lo;
    int c = s1 - s0;
    float inv = 1.0f / (float)(c > 0 ? c : 1);
    for (int f = threadIdx.x; f < F; f += blockDim.x) {
        float acc = 0.0f;
        for (int n = s0; n < s1; ++n) acc += fmaxf(X[(size_t)n * F + f], 0.0f);
        out[(size_t)g * F + f] = acc * inv;
    }
}

// small thread-per-output GEMM (for N=64 layers)
template <bool RELU_OUT>
__global__ void mlp_gemm(const float* __restrict__ A, const float* __restrict__ W,
                         const float* __restrict__ b, float* __restrict__ C,
                         int K, int M, int ldc, int coff) {
    size_t idx = blockIdx.x * (size_t)blockDim.x + threadIdx.x;
    if (idx >= (size_t)NGRAPH * M) return;
    int m = (int)(idx % M);
    size_t g = idx / M;
    const float* ar = A + g * (size_t)K;
    float acc = b[m];
    for (int k = 0; k < K; ++k) acc = fmaf(ar[k], W[(size_t)k * M + m], acc);
    if (RELU_OUT) acc = fmaxf(acc, 0.0f);
    C[g * (size_t)ldc + coff + m] = acc;
}

__global__ void final_kernel(const float* __restrict__ A, const float* __restrict__ w,
                             const float* __restrict__ b, float* __restrict__ out, int K) {
    int g = blockIdx.x * blockDim.x + threadIdx.x;
    if (g >= NGRAPH) return;
    float acc = b[0];
    const float* ar = A + (size_t)g * K;
    for (int k = 0; k < K; ++k) acc = fmaf(ar[k], w[k], acc);
    out[g] = acc;
}

static inline dim3 tgrid(int M, int N, int BM, int BN) {
    return dim3((unsigned)((N + BN - 1) / BN), (unsigned)((M + BM - 1) / BM));
}

// build CSR for one graph (stream-ordered); pos ends as inclusive-end array
static void build_csr(const int* row, const int* col, const float* attr,
                      int N, int E, float* dinv, int* pos,
                      int* rowp, float* coefp, int* bsum, hipStream_t stream) {
    const int B = 256;
    int nb = (N + 255) / 256;
    fill_i32<<<grid_for(N), B, 0, stream>>>(pos, 0, (size_t)N);
    hist_kernel<<<grid_for(E), B, 0, stream>>>(col, E, pos);
    dinv_kernel<<<grid_for(N), B, 0, stream>>>(pos, dinv, N);
    scan_pass1<<<nb, B, 0, stream>>>(pos, bsum, N);
    scan_pass2<<<1, 64, 0, stream>>>(bsum, nb);
    scan_pass3<<<nb, B, 0, stream>>>(pos, bsum, N);
    csr_fill<<<grid_for(E), B, 0, stream>>>(row, col, attr, dinv, pos, rowp, coefp, E);
}

extern "C" void kernel_launch(void* const* d_in, const int* in_sizes, int n_in,
                              void* d_out, int out_size, void* d_ws, size_t ws_size,
                              hipStream_t stream) {
    const float* drug_x  = (const float*)d_in[0];
    const int*   d_ei    = (const int*)d_in[1];
    const float* d_ea    = (const float*)d_in[2];
    const int*   d_batch = (const int*)d_in[3];
    const float* prot_x  = (const float*)d_in[4];
    const int*   p_ei    = (const int*)d_in[5];
    const float* p_ea    = (const float*)d_in[6];
    const int*   p_batch = (const int*)d_in[7];
    const float* dW1 = (const float*)d_in[8];
    const float* dW2 = (const float*)d_in[9];
    const float* dW3 = (const float*)d_in[10];
    const float* dL1_w = (const float*)d_in[11];
    const float* dL1_b = (const float*)d_in[12];
    const float* dL2_w = (const float*)d_in[13];
    const float* dL2_b = (const float*)d_in[14];
    const float* pW1 = (const float*)d_in[15];
    const float* pW2 = (const float*)d_in[16];
    const float* pW3 = (const float*)d_in[17];
    const float* pL1_w = (const float*)d_in[18];
    const float* pL1_b = (const float*)d_in[19];
    const float* pL2_w = (const float*)d_in[20];
    const float* pL2_b = (const float*)d_in[21];
    const float* fW1 = (const float*)d_in[22];
    const float* fb1 = (const float*)d_in[23];
    const float* fW2 = (const float*)d_in[24];
    const float* fb2 = (const float*)d_in[25];
    const float* fW3 = (const float*)d_in[26];
    const float* fb3 = (const float*)d_in[27];
    float* out = (float*)d_out;

    const int Nd = in_sizes[0] / 78;
    const int Ed = in_sizes[1] / 2;
    const int Np = in_sizes[4] / 20;
    const int Ep = in_sizes[5] / 2;
    const int* d_row = d_ei;
    const int* d_col = d_ei + Ed;
    const int* p_row = p_ei;
    const int* p_col = p_ei + Ep;

    // ---- workspace layout (floats); keep total under the proven-safe bound ----
    float* ws = (float*)d_ws;
    size_t off = 0;
    auto align256 = [](size_t n) -> size_t { return (n + 255) & ~(size_t)255; };
    auto take = [&](size_t n) -> float* {
        float* p = ws + off;
        off += align256(n);
        return p;
    };
    float* B1      = take((size_t)Nd * 312);   // GEMM output H
    float* B2      = take((size_t)Nd * 312);   // aggregate output
    float* dinv_d  = take((size_t)Nd);
    float* dinv_p  = take((size_t)Np);
    float* pool    = take((size_t)NGRAPH * 312);
    float* t1      = take((size_t)NGRAPH * 1024);
    float* Cbuf    = take((size_t)NGRAPH * 128);
    float* f2buf   = take((size_t)NGRAPH * 512);
    int*   bsum    = (int*)take(1056);
    // drug CSR (small, dedicated)
    int*   pos_d   = (int*)take((size_t)Nd);
    int*   rowp_d  = (int*)take((size_t)Ed);
    float* coefp_d = take((size_t)Ed);
    // protein CSR lives in the dead tail of B1 (protein uses only B1[0 .. Np*80))
    size_t tail = align256((size_t)Np * 80);
    int*   pos_p   = (int*)(B1 + tail);
    int*   rowp_p  = (int*)(B1 + tail + align256((size_t)Np));
    float* coefp_p = B1 + tail + align256((size_t)Np) + align256((size_t)Ep);
    (void)ws_size;

    const int B = 256;

    // ================= drug branch: 78 -> 78 -> 156 -> 312 =================
    build_csr(d_row, d_col, d_ea, Nd, Ed, dinv_d, pos_d, rowp_d, coefp_d, bsum, stream);

    tgemm<128,128,8,8,8,false,false,false><<<tgrid(Nd,78,128,128), B, 0, stream>>>(
        drug_x, dW1, nullptr, B1, Nd, 78, 78, 78, 0);
    gather_agg<2,32><<<grid_for((size_t)Nd * 32), B, 0, stream>>>(
        pos_d, rowp_d, coefp_d, B1, dinv_d, B2, Nd, 78);

    tgemm<128,128,8,8,8,true,false,false><<<tgrid(Nd,156,128,128), B, 0, stream>>>(
        B2, dW2, nullptr, B1, Nd, 78, 156, 156, 0);
    gather_agg<4,32><<<grid_for((size_t)Nd * 32), B, 0, stream>>>(
        pos_d, rowp_d, coefp_d, B1, dinv_d, B2, Nd, 156);

    tgemm<128,128,8,8,8,true,false,false><<<tgrid(Nd,312,128,128), B, 0, stream>>>(
        B2, dW3, nullptr, B1, Nd, 156, 312, 312, 0);
    gather_agg<4,64><<<grid_for((size_t)Nd * 64), B, 0, stream>>>(
        pos_d, rowp_d, coefp_d, B1, dinv_d, B2, Nd, 312);

    pool_mean<<<NGRAPH, B, 0, stream>>>(B2, d_batch, pool, Nd, 312);

    tgemm<64,128,8,4,8,false,true,true><<<tgrid(NGRAPH,1024,64,128), B, 0, stream>>>(
        pool, dL1_w, dL1_b, t1, NGRAPH, 312, 1024, 1024, 0);
    mlp_gemm<true><<<grid_for((size_t)NGRAPH * 64), B, 0, stream>>>(t1, dL2_w, dL2_b, Cbuf, 1024, 64, 128, 0);

    // ================= protein branch: 20 -> 20 -> 40 -> 80 =================
    // (drug data in B1 tail is dead now; CSR arrays overwrite it)
    build_csr(p_row, p_col, p_ea, Np, Ep, dinv_p, pos_p, rowp_p, coefp_p, bsum, stream);

    tgemm<128,64,8,8,4,false,false,false><<<tgrid(Np,20,128,64), B, 0, stream>>>(
        prot_x, pW1, nullptr, B1, Np, 20, 20, 20, 0);
    gather_agg<4,8><<<grid_for((size_t)Np * 8), B, 0, stream>>>(
        pos_p, rowp_p, coefp_p, B1, dinv_p, B2, Np, 20);

    tgemm<128,64,8,8,4,true,false,false><<<tgrid(Np,40,128,64), B, 0, stream>>>(
        B2, pW2, nullptr, B1, Np, 20, 40, 40, 0);
    gather_agg<4,16><<<grid_for((size_t)Np * 16), B, 0, stream>>>(
        pos_p, rowp_p, coefp_p, B1, dinv_p, B2, Np, 40);

    tgemm<128,64,8,8,4,true,false,false><<<tgrid(Np,80,128,64), B, 0, stream>>>(
        B2, pW3, nullptr, B1, Np, 40, 80, 80, 0);
    gather_agg<4,32><<<grid_for((size_t)Np * 32), B, 0, stream>>>(
        pos_p, rowp_p, coefp_p, B1, dinv_p, B2, Np, 80);

    pool_mean<<<NGRAPH, B, 0, stream>>>(B2, p_batch, pool, Np, 80);

    tgemm<64,128,8,4,8,false,true,true><<<tgrid(NGRAPH,1024,64,128), B, 0, stream>>>(
        pool, pL1_w, pL1_b, t1, NGRAPH, 80, 1024, 1024, 0);
    mlp_gemm<true><<<grid_for((size_t)NGRAPH * 64), B, 0, stream>>>(t1, pL2_w, pL2_b, Cbuf, 1024, 64, 128, 64);

    // ================= head: 128 -> 1024 -> 512 -> 1 =================
    tgemm<64,128,8,4,8,false,true,true><<<tgrid(NGRAPH,1024,64,128), B, 0, stream>>>(
        Cbuf, fW1, fb1, t1, NGRAPH, 128, 1024, 1024, 0);
    tgemm<64,128,8,4,8,false,true,true><<<tgrid(NGRAPH,512,64,128), B, 0, stream>>>(
        t1, fW2, fb2, f2buf, NGRAPH, 1024, 512, 512, 0);
    final_kernel<<<grid_for(NGRAPH), B, 0, stream>>>(f2buf, fW3, fb3, out, 512);
}

// Round 8
// 2278.852 us; speedup vs baseline: 4.8836x; 1.4045x over previous
//
#include <hip/hip_runtime.h>
#include <math.h>

#define NGRAPH 512

static inline unsigned grid_for(size_t n, int block = 256) {
    return (unsigned)((n + block - 1) / block);
}

__global__ void fill_i32(int* __restrict__ p, int v, size_t n) {
    size_t i = blockIdx.x * (size_t)blockDim.x + threadIdx.x;
    if (i < n) p[i] = v;
}

// histogram of destination indices
__global__ void hist_kernel(const int* __restrict__ col, int E, int* __restrict__ cnt) {
    size_t i = blockIdx.x * (size_t)blockDim.x + threadIdx.x;
    if (i < (size_t)E) atomicAdd(&cnt[col[i]], 1);
}

// dinv[n] = (cnt[n] + 1)^-0.5   (+1 = self loop)
__global__ void dinv_kernel(const int* __restrict__ cnt, float* __restrict__ d, int n) {
    size_t i = blockIdx.x * (size_t)blockDim.x + threadIdx.x;
    if (i < (size_t)n) d[i] = 1.0f / sqrtf((float)cnt[i] + 1.0f);
}

// ---- 3-pass exclusive scan over pos[] (in-place; n <= ~262k) ----
__global__ void scan_pass1(const int* __restrict__ in, int* __restrict__ bsum, int n) {
    __shared__ int sdata[256];
    int tid = threadIdx.x;
    int i = blockIdx.x * 256 + tid;
    int v = (i < n) ? in[i] : 0;
    sdata[tid] = v;
    __syncthreads();
    for (int s = 128; s > 0; s >>= 1) {
        if (tid < s) sdata[tid] += sdata[tid + s];
        __syncthreads();
    }
    if (tid == 0) bsum[blockIdx.x] = sdata[0];
}

__global__ void scan_pass2(int* __restrict__ bsum, int nb) {
    if (threadIdx.x == 0 && blockIdx.x == 0) {
        int acc = 0;
        for (int i = 0; i < nb; ++i) { int t = bsum[i]; bsum[i] = acc; acc += t; }
        bsum[nb] = acc;
    }
}

// in-place: pos[i] <- exclusive prefix
__global__ void scan_pass3(int* __restrict__ pos, const int* __restrict__ bsum, int n) {
    __shared__ int sdata[256];
    int tid = threadIdx.x;
    int i = blockIdx.x * 256 + tid;
    int v = (i < n) ? pos[i] : 0;
    sdata[tid] = v;
    __syncthreads();
    for (int ofs = 1; ofs < 256; ofs <<= 1) {
        int t = (tid >= ofs) ? sdata[tid - ofs] : 0;
        __syncthreads();
        sdata[tid] += t;
        __syncthreads();
    }
    if (i < n) pos[i] = sdata[tid] - v + bsum[blockIdx.x];
}

// CSR fill: slot = pos[col[e]]++; after this kernel pos[i] == inclusive end of node i
__global__ void csr_fill(const int* __restrict__ row, const int* __restrict__ col,
                         const float* __restrict__ attr, const float* __restrict__ dinv,
                         int* __restrict__ pos, int* __restrict__ rowp,
                         float* __restrict__ coefp, int E) {
    size_t i = blockIdx.x * (size_t)blockDim.x + threadIdx.x;
    if (i >= (size_t)E) return;
    int r = row[i], c = col[i];
    int slot = atomicAdd(&pos[c], 1);
    rowp[slot] = r;
    coefp[slot] = dinv[r] * attr[i] * dinv[c];
}

// Tiled GEMM: C[m][n] = act_out(act_in(A[m][:]) @ W[:][n] + bias[n])
template <int BM, int BN, int BK, int TM, int TN,
          bool RELU_IN, bool RELU_OUT, bool BIAS>
__global__ __launch_bounds__(256) void tgemm(
        const float* __restrict__ A, const float* __restrict__ W,
        const float* __restrict__ bias, float* __restrict__ C,
        int M, int K, int N, int ldc, int coff) {
    const int tid = threadIdx.x;
    const int nthread_n = BN / TN;
    const int tx = tid % nthread_n;
    const int ty = tid / nthread_n;
    const int m0 = blockIdx.y * BM;
    const int n0 = blockIdx.x * BN;

    __shared__ float As[BK][BM + 4];
    __shared__ float Ws[BK][BN];

    float acc[TM][TN];
#pragma unroll
    for (int i = 0; i < TM; ++i)
#pragma unroll
        for (int j = 0; j < TN; ++j) acc[i][j] = 0.0f;

    for (int k0 = 0; k0 < K; k0 += BK) {
        __syncthreads();
        for (int idx = tid; idx < BM * BK; idx += 256) {
            int k = idx % BK;
            int m = idx / BK;
            float v = 0.0f;
            int gm = m0 + m, gk = k0 + k;
            if (gm < M && gk < K) {
                v = A[(size_t)gm * K + gk];
                if (RELU_IN) v = fmaxf(v, 0.0f);
            }
            As[k][m] = v;
        }
        for (int idx = tid; idx < BK * BN; idx += 256) {
            int n = idx % BN;
            int k = idx / BN;
            float v = 0.0f;
            int gk = k0 + k, gn = n0 + n;
            if (gk < K && gn < N) v = W[(size_t)gk * N + gn];
            Ws[k][n] = v;
        }
        __syncthreads();
#pragma unroll
        for (int kk = 0; kk < BK; ++kk) {
            float a[TM], b[TN];
#pragma unroll
            for (int i = 0; i < TM; ++i) a[i] = As[kk][ty * TM + i];
#pragma unroll
            for (int j = 0; j < TN; ++j) b[j] = Ws[kk][tx * TN + j];
#pragma unroll
            for (int i = 0; i < TM; ++i)
#pragma unroll
                for (int j = 0; j < TN; ++j) acc[i][j] = fmaf(a[i], b[j], acc[i][j]);
        }
    }

#pragma unroll
    for (int i = 0; i < TM; ++i) {
        int gm = m0 + ty * TM + i;
        if (gm >= M) continue;
#pragma unroll
        for (int j = 0; j < TN; ++j) {
            int gn = n0 + tx * TN + j;
            if (gn >= N) continue;
            float v = acc[i][j];
            if (BIAS) v += bias[gn];
            if (RELU_OUT) v = fmaxf(v, 0.0f);
            C[(size_t)gm * ldc + coff + gn] = v;
        }
    }
}

template <int V> struct VT {};
template <> struct VT<2> { using T = float2; };
template <> struct VT<4> { using T = float4; };

// CSR gather-aggregate: AGG[n][:] = dinv[n]^2 * H[n][:] + sum_t coefp[t] * H[rowp[t]][:]
template <int V, int LPG>
__global__ void gather_agg(const int* __restrict__ pos, const int* __restrict__ rowp,
                           const float* __restrict__ coefp, const float* __restrict__ H,
                           const float* __restrict__ dinv, float* __restrict__ AGG,
                           int N, int F) {
    using VecT = typename VT<V>::T;
    union U { VecT v; float a[V]; };
    const int gpb = 256 / LPG;
    int gid = blockIdx.x * gpb + threadIdx.x / LPG;
    int lane = threadIdx.x % LPG;
    if (gid >= N) return;
    int start = (gid == 0) ? 0 : pos[gid - 1];
    int end = pos[gid];
    float s = dinv[gid];
    float s2 = s * s;
    for (int f = lane * V; f < F; f += LPG * V) {
        U acc;
        acc.v = *reinterpret_cast<const VecT*>(H + (size_t)gid * F + f);
#pragma unroll
        for (int j = 0; j < V; ++j) acc.a[j] *= s2;
        for (int t = start; t < end; ++t) {
            int r = rowp[t];
            float cf = coefp[t];
            U h;
            h.v = *reinterpret_cast<const VecT*>(H + (size_t)r * F + f);
#pragma unroll
            for (int j = 0; j < V; ++j) acc.a[j] = fmaf(cf, h.a[j], acc.a[j]);
        }
        *reinterpret_cast<VecT*>(AGG + (size_t)gid * F + f) = acc.v;
    }
}

// segment mean-pool over sorted batch: out[g][f] = mean over nodes of relu(X[n][f])
__global__ void pool_mean(const float* __restrict__ X, const int* __restrict__ batch,
                          float* __restrict__ out, int N, int F) {
    int g = blockIdx.x;
    int lo = 0, hi = N;
    while (lo < hi) { int mid = (lo + hi) >> 1; if (batch[mid] < g) lo = mid + 1; else hi = mid; }
    int s0 = lo;
    hi = N;
    while (lo < hi) { int mid = (lo + hi) >> 1; if (batch[mid] < g + 1) lo = mid + 1; else hi = mid; }
    int s1 = lo;
    int c = s1 - s0;
    float inv = 1.0f / (float)(c > 0 ? c : 1);
    for (int f = threadIdx.x; f < F; f += blockDim.x) {
        float acc = 0.0f;
        for (int n = s0; n < s1; ++n) acc += fmaxf(X[(size_t)n * F + f], 0.0f);
        out[(size_t)g * F + f] = acc * inv;
    }
}

// Skinny MLP GEMM: one block per (graph g, 64-wide m-chunk).
// 256 threads = 64 m-lanes x 4 K-quarters. A row staged in LDS.
// C[g][coff + m0 + m] = act(A[g][:K] . W[:,m0+m] + bias[m0+m])
template <bool RELU_OUT>
__global__ __launch_bounds__(256) void skinny_gemm(
        const float* __restrict__ A, const float* __restrict__ W,
        const float* __restrict__ bias, float* __restrict__ C,
        int K, int M, int ldc, int coff) {
    __shared__ float As[1024];          // K <= 1024
    __shared__ float red[4][64];
    const int tid = threadIdx.x;
    const int m_l = tid & 63;
    const int q = tid >> 6;
    const int g = blockIdx.y;
    const int m0 = blockIdx.x * 64;

    for (int idx = tid; idx < K; idx += 256) As[idx] = A[(size_t)g * K + idx];
    __syncthreads();

    const int Kq = (K + 3) >> 2;
    const int ks = q * Kq;
    const int ke = (ks + Kq < K) ? ks + Kq : K;
    const int m = m0 + m_l;
    float acc = 0.0f;
    if (m < M) {
        for (int k = ks; k < ke; ++k) acc = fmaf(As[k], W[(size_t)k * M + m], acc);
    }
    red[q][m_l] = acc;
    __syncthreads();
    if (q == 0 && m < M) {
        float v = red[0][m_l] + red[1][m_l] + red[2][m_l] + red[3][m_l] + bias[m];
        if (RELU_OUT) v = fmaxf(v, 0.0f);
        C[(size_t)g * ldc + coff + m] = v;
    }
}

// final: out[g] = A[g][:K] . w + b[0], one wave per graph
__global__ void final_kernel(const float* __restrict__ A, const float* __restrict__ w,
                             const float* __restrict__ b, float* __restrict__ out, int K) {
    int wave = (blockIdx.x * blockDim.x + threadIdx.x) >> 6;
    int lane = threadIdx.x & 63;
    if (wave >= NGRAPH) return;
    const float* ar = A + (size_t)wave * K;
    float acc = 0.0f;
    for (int k = lane; k < K; k += 64) acc = fmaf(ar[k], w[k], acc);
#pragma unroll
    for (int s = 32; s > 0; s >>= 1) acc += __shfl_down(acc, s, 64);
    if (lane == 0) out[wave] = acc + b[0];
}

static inline dim3 tgrid(int M, int N, int BM, int BN) {
    return dim3((unsigned)((N + BN - 1) / BN), (unsigned)((M + BM - 1) / BM));
}

// build CSR for one graph (stream-ordered); pos ends as inclusive-end array
static void build_csr(const int* row, const int* col, const float* attr,
                      int N, int E, float* dinv, int* pos,
                      int* rowp, float* coefp, int* bsum, hipStream_t stream) {
    const int B = 256;
    int nb = (N + 255) / 256;
    fill_i32<<<grid_for(N), B, 0, stream>>>(pos, 0, (size_t)N);
    hist_kernel<<<grid_for(E), B, 0, stream>>>(col, E, pos);
    dinv_kernel<<<grid_for(N), B, 0, stream>>>(pos, dinv, N);
    scan_pass1<<<nb, B, 0, stream>>>(pos, bsum, N);
    scan_pass2<<<1, 64, 0, stream>>>(bsum, nb);
    scan_pass3<<<nb, B, 0, stream>>>(pos, bsum, N);
    csr_fill<<<grid_for(E), B, 0, stream>>>(row, col, attr, dinv, pos, rowp, coefp, E);
}

extern "C" void kernel_launch(void* const* d_in, const int* in_sizes, int n_in,
                              void* d_out, int out_size, void* d_ws, size_t ws_size,
                              hipStream_t stream) {
    const float* drug_x  = (const float*)d_in[0];
    const int*   d_ei    = (const int*)d_in[1];
    const float* d_ea    = (const float*)d_in[2];
    const int*   d_batch = (const int*)d_in[3];
    const float* prot_x  = (const float*)d_in[4];
    const int*   p_ei    = (const int*)d_in[5];
    const float* p_ea    = (const float*)d_in[6];
    const int*   p_batch = (const int*)d_in[7];
    const float* dW1 = (const float*)d_in[8];
    const float* dW2 = (const float*)d_in[9];
    const float* dW3 = (const float*)d_in[10];
    const float* dL1_w = (const float*)d_in[11];
    const float* dL1_b = (const float*)d_in[12];
    const float* dL2_w = (const float*)d_in[13];
    const float* dL2_b = (const float*)d_in[14];
    const float* pW1 = (const float*)d_in[15];
    const float* pW2 = (const float*)d_in[16];
    const float* pW3 = (const float*)d_in[17];
    const float* pL1_w = (const float*)d_in[18];
    const float* pL1_b = (const float*)d_in[19];
    const float* pL2_w = (const float*)d_in[20];
    const float* pL2_b = (const float*)d_in[21];
    const float* fW1 = (const float*)d_in[22];
    const float* fb1 = (const float*)d_in[23];
    const float* fW2 = (const float*)d_in[24];
    const float* fb2 = (const float*)d_in[25];
    const float* fW3 = (const float*)d_in[26];
    const float* fb3 = (const float*)d_in[27];
    float* out = (float*)d_out;

    const int Nd = in_sizes[0] / 78;
    const int Ed = in_sizes[1] / 2;
    const int Np = in_sizes[4] / 20;
    const int Ep = in_sizes[5] / 2;
    const int* d_row = d_ei;
    const int* d_col = d_ei + Ed;
    const int* p_row = p_ei;
    const int* p_col = p_ei + Ep;

    // ---- workspace layout (floats); keep total under the proven-safe bound ----
    float* ws = (float*)d_ws;
    size_t off = 0;
    auto align256 = [](size_t n) -> size_t { return (n + 255) & ~(size_t)255; };
    auto take = [&](size_t n) -> float* {
        float* p = ws + off;
        off += align256(n);
        return p;
    };
    float* B1      = take((size_t)Nd * 312);   // GEMM output H
    float* B2      = take((size_t)Nd * 312);   // aggregate output
    float* dinv_d  = take((size_t)Nd);
    float* dinv_p  = take((size_t)Np);
    float* pool    = take((size_t)NGRAPH * 312);
    float* t1      = take((size_t)NGRAPH * 1024);
    float* Cbuf    = take((size_t)NGRAPH * 128);
    float* f2buf   = take((size_t)NGRAPH * 512);
    int*   bsum    = (int*)take(1056);
    // drug CSR (small, dedicated)
    int*   pos_d   = (int*)take((size_t)Nd);
    int*   rowp_d  = (int*)take((size_t)Ed);
    float* coefp_d = take((size_t)Ed);
    // protein CSR lives in the dead tail of B1 (protein uses only B1[0 .. Np*80))
    size_t tail = align256((size_t)Np * 80);
    int*   pos_p   = (int*)(B1 + tail);
    int*   rowp_p  = (int*)(B1 + tail + align256((size_t)Np));
    float* coefp_p = B1 + tail + align256((size_t)Np) + align256((size_t)Ep);
    (void)ws_size;

    const int B = 256;

    // ================= drug branch: 78 -> 78 -> 156 -> 312 =================
    build_csr(d_row, d_col, d_ea, Nd, Ed, dinv_d, pos_d, rowp_d, coefp_d, bsum, stream);

    tgemm<128,128,8,8,8,false,false,false><<<tgrid(Nd,78,128,128), B, 0, stream>>>(
        drug_x, dW1, nullptr, B1, Nd, 78, 78, 78, 0);
    gather_agg<2,32><<<grid_for((size_t)Nd * 32), B, 0, stream>>>(
        pos_d, rowp_d, coefp_d, B1, dinv_d, B2, Nd, 78);

    tgemm<128,128,8,8,8,true,false,false><<<tgrid(Nd,156,128,128), B, 0, stream>>>(
        B2, dW2, nullptr, B1, Nd, 78, 156, 156, 0);
    gather_agg<4,32><<<grid_for((size_t)Nd * 32), B, 0, stream>>>(
        pos_d, rowp_d, coefp_d, B1, dinv_d, B2, Nd, 156);

    tgemm<128,128,8,8,8,true,false,false><<<tgrid(Nd,312,128,128), B, 0, stream>>>(
        B2, dW3, nullptr, B1, Nd, 156, 312, 312, 0);
    gather_agg<4,64><<<grid_for((size_t)Nd * 64), B, 0, stream>>>(
        pos_d, rowp_d, coefp_d, B1, dinv_d, B2, Nd, 312);

    pool_mean<<<NGRAPH, B, 0, stream>>>(B2, d_batch, pool, Nd, 312);

    skinny_gemm<true><<<dim3(16, NGRAPH), B, 0, stream>>>(pool, dL1_w, dL1_b, t1, 312, 1024, 1024, 0);
    skinny_gemm<true><<<dim3(1, NGRAPH), B, 0, stream>>>(t1, dL2_w, dL2_b, Cbuf, 1024, 64, 128, 0);

    // ================= protein branch: 20 -> 20 -> 40 -> 80 =================
    build_csr(p_row, p_col, p_ea, Np, Ep, dinv_p, pos_p, rowp_p, coefp_p, bsum, stream);

    tgemm<128,64,8,8,4,false,false,false><<<tgrid(Np,20,128,64), B, 0, stream>>>(
        prot_x, pW1, nullptr, B1, Np, 20, 20, 20, 0);
    gather_agg<4,8><<<grid_for((size_t)Np * 8), B, 0, stream>>>(
        pos_p, rowp_p, coefp_p, B1, dinv_p, B2, Np, 20);

    tgemm<128,64,8,8,4,true,false,false><<<tgrid(Np,40,128,64), B, 0, stream>>>(
        B2, pW2, nullptr, B1, Np, 20, 40, 40, 0);
    gather_agg<4,16><<<grid_for((size_t)Np * 16), B, 0, stream>>>(
        pos_p, rowp_p, coefp_p, B1, dinv_p, B2, Np, 40);

    tgemm<128,64,8,8,4,true,false,false><<<tgrid(Np,80,128,64), B, 0, stream>>>(
        B2, pW3, nullptr, B1, Np, 40, 80, 80, 0);
    gather_agg<4,32><<<grid_for((size_t)Np * 32), B, 0, stream>>>(
        pos_p, rowp_p, coefp_p, B1, dinv_p, B2, Np, 80);

    pool_mean<<<NGRAPH, B, 0, stream>>>(B2, p_batch, pool, Np, 80);

    skinny_gemm<true><<<dim3(16, NGRAPH), B, 0, stream>>>(pool, pL1_w, pL1_b, t1, 80, 1024, 1024, 0);
    skinny_gemm<true><<<dim3(1, NGRAPH), B, 0, stream>>>(t1, pL2_w, pL2_b, Cbuf, 1024, 64, 128, 64);

    // ================= head: 128 -> 1024 -> 512 -> 1 =================
    skinny_gemm<true><<<dim3(16, NGRAPH), B, 0, stream>>>(Cbuf, fW1, fb1, t1, 128, 1024, 1024, 0);
    skinny_gemm<true><<<dim3(8, NGRAPH), B, 0, stream>>>(t1, fW2, fb2, f2buf, 1024, 512, 512, 0);
    final_kernel<<<grid_for((size_t)NGRAPH * 64), B, 0, stream>>>(f2buf, fW3, fb3, out, 512);
}

// Round 9
// 2034.369 us; speedup vs baseline: 5.4705x; 1.1202x over previous
//
#include <hip/hip_runtime.h>
#include <math.h>

#define NGRAPH 512

static inline unsigned grid_for(size_t n, int block = 256) {
    return (unsigned)((n + block - 1) / block);
}

__global__ void fill_i32(int* __restrict__ p, int v, size_t n) {
    size_t i = blockIdx.x * (size_t)blockDim.x + threadIdx.x;
    if (i < n) p[i] = v;
}

// histogram of destination indices
__global__ void hist_kernel(const int* __restrict__ col, int E, int* __restrict__ cnt) {
    size_t i = blockIdx.x * (size_t)blockDim.x + threadIdx.x;
    if (i < (size_t)E) atomicAdd(&cnt[col[i]], 1);
}

// dinv[n] = (cnt[n] + 1)^-0.5   (+1 = self loop)
__global__ void dinv_kernel(const int* __restrict__ cnt, float* __restrict__ d, int n) {
    size_t i = blockIdx.x * (size_t)blockDim.x + threadIdx.x;
    if (i < (size_t)n) d[i] = 1.0f / sqrtf((float)cnt[i] + 1.0f);
}

// ---- 3-pass exclusive scan over pos[] (in-place) ----
__global__ void scan_pass1(const int* __restrict__ in, int* __restrict__ bsum, int n) {
    __shared__ int sdata[256];
    int tid = threadIdx.x;
    int i = blockIdx.x * 256 + tid;
    int v = (i < n) ? in[i] : 0;
    sdata[tid] = v;
    __syncthreads();
    for (int s = 128; s > 0; s >>= 1) {
        if (tid < s) sdata[tid] += sdata[tid + s];
        __syncthreads();
    }
    if (tid == 0) bsum[blockIdx.x] = sdata[0];
}

__global__ void scan_pass2(int* __restrict__ bsum, int nb) {
    if (threadIdx.x == 0 && blockIdx.x == 0) {
        int acc = 0;
        for (int i = 0; i < nb; ++i) { int t = bsum[i]; bsum[i] = acc; acc += t; }
        bsum[nb] = acc;
    }
}

__global__ void scan_pass3(int* __restrict__ pos, const int* __restrict__ bsum, int n) {
    __shared__ int sdata[256];
    int tid = threadIdx.x;
    int i = blockIdx.x * 256 + tid;
    int v = (i < n) ? pos[i] : 0;
    sdata[tid] = v;
    __syncthreads();
    for (int ofs = 1; ofs < 256; ofs <<= 1) {
        int t = (tid >= ofs) ? sdata[tid - ofs] : 0;
        __syncthreads();
        sdata[tid] += t;
        __syncthreads();
    }
    if (i < n) pos[i] = sdata[tid] - v + bsum[blockIdx.x];
}

// CSR fill: slot = pos[col[e]]++; after this kernel pos[i] == inclusive end of node i
__global__ void csr_fill(const int* __restrict__ row, const int* __restrict__ col,
                         const float* __restrict__ attr, const float* __restrict__ dinv,
                         int* __restrict__ pos, int* __restrict__ rowp,
                         float* __restrict__ coefp, int E) {
    size_t i = blockIdx.x * (size_t)blockDim.x + threadIdx.x;
    if (i >= (size_t)E) return;
    int r = row[i], c = col[i];
    int slot = atomicAdd(&pos[c], 1);
    rowp[slot] = r;
    coefp[slot] = dinv[r] * attr[i] * dinv[c];
}

// Tiled GEMM: C[m][n] = act_out(A[m][:] @ W[:][n] + bias[n])
// B-fragment is TN/4 strided float4s (lane-contiguous 16B chunks -> 2-way LDS
// aliasing = free) instead of one contiguous TN-float run (4-way conflict).
template <int BM, int BN, int BK, int TM, int TN, bool RELU_OUT, bool BIAS>
__global__ __launch_bounds__(256) void tgemm(
        const float* __restrict__ A, const float* __restrict__ W,
        const float* __restrict__ bias, float* __restrict__ C,
        int M, int K, int N, int ldc, int coff) {
    constexpr int NT = BN / TN;        // threads along n (16)
    constexpr int NJ = TN / 4;         // float4s per thread in n
    constexpr int NI = TM / 4;         // float4s per thread in m
    const int tid = threadIdx.x;
    const int tx = tid % NT;
    const int ty = tid / NT;
    const int m0 = blockIdx.y * BM;
    const int n0 = blockIdx.x * BN;

    __shared__ float As[BK][BM + 4];   // transposed A tile; row stride 132 floats (528B, 16B-aligned)
    __shared__ float Ws[BK][BN];

    float acc[TM][TN];
#pragma unroll
    for (int i = 0; i < TM; ++i)
#pragma unroll
        for (int j = 0; j < TN; ++j) acc[i][j] = 0.0f;

    for (int k0 = 0; k0 < K; k0 += BK) {
        __syncthreads();
        for (int idx = tid; idx < BM * BK; idx += 256) {
            int k = idx % BK;
            int m = idx / BK;
            float v = 0.0f;
            int gm = m0 + m, gk = k0 + k;
            if (gm < M && gk < K) v = A[(size_t)gm * K + gk];
            As[k][m] = v;
        }
        for (int idx = tid; idx < BK * BN; idx += 256) {
            int n = idx % BN;
            int k = idx / BN;
            float v = 0.0f;
            int gk = k0 + k, gn = n0 + n;
            if (gk < K && gn < N) v = W[(size_t)gk * N + gn];
            Ws[k][n] = v;
        }
        __syncthreads();
#pragma unroll
        for (int kk = 0; kk < BK; ++kk) {
            const float4* As4 = reinterpret_cast<const float4*>(&As[kk][0]);
            const float4* Ws4 = reinterpret_cast<const float4*>(&Ws[kk][0]);
            float a[TM], b[TN];
#pragma unroll
            for (int ii = 0; ii < NI; ++ii)
                *reinterpret_cast<float4*>(&a[ii * 4]) = As4[ty * NI + ii];
#pragma unroll
            for (int jj = 0; jj < NJ; ++jj)
                *reinterpret_cast<float4*>(&b[jj * 4]) = Ws4[tx + NT * jj];
#pragma unroll
            for (int i = 0; i < TM; ++i)
#pragma unroll
                for (int j = 0; j < TN; ++j) acc[i][j] = fmaf(a[i], b[j], acc[i][j]);
        }
    }

#pragma unroll
    for (int i = 0; i < TM; ++i) {
        int gm = m0 + ty * TM + i;
        if (gm >= M) continue;
#pragma unroll
        for (int jj = 0; jj < NJ; ++jj) {
#pragma unroll
            for (int c = 0; c < 4; ++c) {
                int gn = n0 + jj * (NT * 4) + tx * 4 + c;
                if (gn >= N) continue;
                float v = acc[i][jj * 4 + c];
                if (BIAS) v += bias[gn];
                if (RELU_OUT) v = fmaxf(v, 0.0f);
                C[(size_t)gm * ldc + coff + gn] = v;
            }
        }
    }
}

template <int V> struct VT {};
template <> struct VT<2> { using T = float2; };
template <> struct VT<4> { using T = float4; };

// CSR gather-aggregate: AGG[n][:] = dinv[n]^2 * X[n][:] + sum_t coefp[t] * X[rowp[t]][:]
template <int V, int LPG>
__global__ void gather_agg(const int* __restrict__ pos, const int* __restrict__ rowp,
                           const float* __restrict__ coefp, const float* __restrict__ X,
                           const float* __restrict__ dinv, float* __restrict__ AGG,
                           int N, int F) {
    using VecT = typename VT<V>::T;
    union U { VecT v; float a[V]; };
    const int gpb = 256 / LPG;
    int gid = blockIdx.x * gpb + threadIdx.x / LPG;
    int lane = threadIdx.x % LPG;
    if (gid >= N) return;
    int start = (gid == 0) ? 0 : pos[gid - 1];
    int end = pos[gid];
    float s = dinv[gid];
    float s2 = s * s;
    for (int f = lane * V; f < F; f += LPG * V) {
        U acc;
        acc.v = *reinterpret_cast<const VecT*>(X + (size_t)gid * F + f);
#pragma unroll
        for (int j = 0; j < V; ++j) acc.a[j] *= s2;
        for (int t = start; t < end; ++t) {
            int r = rowp[t];
            float cf = coefp[t];
            U h;
            h.v = *reinterpret_cast<const VecT*>(X + (size_t)r * F + f);
#pragma unroll
            for (int j = 0; j < V; ++j) acc.a[j] = fmaf(cf, h.a[j], acc.a[j]);
        }
        *reinterpret_cast<VecT*>(AGG + (size_t)gid * F + f) = acc.v;
    }
}

// segment mean-pool over sorted batch: out[g][f] = mean over nodes of relu(X[n][f])
__global__ void pool_mean(const float* __restrict__ X, const int* __restrict__ batch,
                          float* __restrict__ out, int N, int F) {
    int g = blockIdx.x;
    int lo = 0, hi = N;
    while (lo < hi) { int mid = (lo + hi) >> 1; if (batch[mid] < g) lo = mid + 1; else hi = mid; }
    int s0 = lo;
    hi = N;
    while (lo < hi) { int mid = (lo + hi) >> 1; if (batch[mid] < g + 1) lo = mid + 1; else hi = mid; }
    int s1 = lo;
    int c = s1 - s0;
    float inv = 1.0f / (float)(c > 0 ? c : 1);
    for (int f = threadIdx.x; f < F; f += blockDim.x) {
        float acc = 0.0f;
        for (int n = s0; n < s1; ++n) acc += fmaxf(X[(size_t)n * F + f], 0.0f);
        out[(size_t)g * F + f] = acc * inv;
    }
}

// Skinny MLP GEMM: one block per (graph g, 64-wide m-chunk).
template <bool RELU_OUT>
__global__ __launch_bounds__(256) void skinny_gemm(
        const float* __restrict__ A, const float* __restrict__ W,
        const float* __restrict__ bias, float* __restrict__ C,
        int K, int M, int ldc, int coff) {
    __shared__ float As[1024];          // K <= 1024
    __shared__ float red[4][64];
    const int tid = threadIdx.x;
    const int m_l = tid & 63;
    const int q = tid >> 6;
    const int g = blockIdx.y;
    const int m0 = blockIdx.x * 64;

    for (int idx = tid; idx < K; idx += 256) As[idx] = A[(size_t)g * K + idx];
    __syncthreads();

    const int Kq = (K + 3) >> 2;
    const int ks = q * Kq;
    const int ke = (ks + Kq < K) ? ks + Kq : K;
    const int m = m0 + m_l;
    float acc = 0.0f;
    if (m < M) {
        for (int k = ks; k < ke; ++k) acc = fmaf(As[k], W[(size_t)k * M + m], acc);
    }
    red[q][m_l] = acc;
    __syncthreads();
    if (q == 0 && m < M) {
        float v = red[0][m_l] + red[1][m_l] + red[2][m_l] + red[3][m_l] + bias[m];
        if (RELU_OUT) v = fmaxf(v, 0.0f);
        C[(size_t)g * ldc + coff + m] = v;
    }
}

// final: out[g] = A[g][:K] . w + b[0], one wave per graph
__global__ void final_kernel(const float* __restrict__ A, const float* __restrict__ w,
                             const float* __restrict__ b, float* __restrict__ out, int K) {
    int wave = (blockIdx.x * blockDim.x + threadIdx.x) >> 6;
    int lane = threadIdx.x & 63;
    if (wave >= NGRAPH) return;
    const float* ar = A + (size_t)wave * K;
    float acc = 0.0f;
    for (int k = lane; k < K; k += 64) acc = fmaf(ar[k], w[k], acc);
#pragma unroll
    for (int s = 32; s > 0; s >>= 1) acc += __shfl_down(acc, s, 64);
    if (lane == 0) out[wave] = acc + b[0];
}

static inline dim3 tgrid(int M, int N, int BM, int BN) {
    return dim3((unsigned)((N + BN - 1) / BN), (unsigned)((M + BM - 1) / BM));
}

// build CSR for one graph (stream-ordered); pos ends as inclusive-end array
static void build_csr(const int* row, const int* col, const float* attr,
                      int N, int E, float* dinv, int* pos,
                      int* rowp, float* coefp, int* bsum, hipStream_t stream) {
    const int B = 256;
    int nb = (N + 255) / 256;
    fill_i32<<<grid_for(N), B, 0, stream>>>(pos, 0, (size_t)N);
    hist_kernel<<<grid_for(E), B, 0, stream>>>(col, E, pos);
    dinv_kernel<<<grid_for(N), B, 0, stream>>>(pos, dinv, N);
    scan_pass1<<<nb, B, 0, stream>>>(pos, bsum, N);
    scan_pass2<<<1, 64, 0, stream>>>(bsum, nb);
    scan_pass3<<<nb, B, 0, stream>>>(pos, bsum, N);
    csr_fill<<<grid_for(E), B, 0, stream>>>(row, col, attr, dinv, pos, rowp, coefp, E);
}

extern "C" void kernel_launch(void* const* d_in, const int* in_sizes, int n_in,
                              void* d_out, int out_size, void* d_ws, size_t ws_size,
                              hipStream_t stream) {
    const float* drug_x  = (const float*)d_in[0];
    const int*   d_ei    = (const int*)d_in[1];
    const float* d_ea    = (const float*)d_in[2];
    const int*   d_batch = (const int*)d_in[3];
    const float* prot_x  = (const float*)d_in[4];
    const int*   p_ei    = (const int*)d_in[5];
    const float* p_ea    = (const float*)d_in[6];
    const int*   p_batch = (const int*)d_in[7];
    const float* dW1 = (const float*)d_in[8];
    const float* dW2 = (const float*)d_in[9];
    const float* dW3 = (const float*)d_in[10];
    const float* dL1_w = (const float*)d_in[11];
    const float* dL1_b = (const float*)d_in[12];
    const float* dL2_w = (const float*)d_in[13];
    const float* dL2_b = (const float*)d_in[14];
    const float* pW1 = (const float*)d_in[15];
    const float* pW2 = (const float*)d_in[16];
    const float* pW3 = (const float*)d_in[17];
    const float* pL1_w = (const float*)d_in[18];
    const float* pL1_b = (const float*)d_in[19];
    const float* pL2_w = (const float*)d_in[20];
    const float* pL2_b = (const float*)d_in[21];
    const float* fW1 = (const float*)d_in[22];
    const float* fb1 = (const float*)d_in[23];
    const float* fW2 = (const float*)d_in[24];
    const float* fb2 = (const float*)d_in[25];
    const float* fW3 = (const float*)d_in[26];
    const float* fb3 = (const float*)d_in[27];
    float* out = (float*)d_out;

    const int Nd = in_sizes[0] / 78;
    const int Ed = in_sizes[1] / 2;
    const int Np = in_sizes[4] / 20;
    const int Ep = in_sizes[5] / 2;
    const int* d_row = d_ei;
    const int* d_col = d_ei + Ed;
    const int* p_row = p_ei;
    const int* p_col = p_ei + Ep;

    // ---- workspace layout (floats); proven-safe total ----
    float* ws = (float*)d_ws;
    size_t off = 0;
    auto align256 = [](size_t n) -> size_t { return (n + 255) & ~(size_t)255; };
    auto take = [&](size_t n) -> float* {
        float* p = ws + off;
        off += align256(n);
        return p;
    };
    float* B1      = take((size_t)Nd * 312);   // GEMM output H / conv outputs
    float* B2      = take((size_t)Nd * 312);   // aggregate output
    float* dinv_d  = take((size_t)Nd);
    float* dinv_p  = take((size_t)Np);
    float* pool    = take((size_t)NGRAPH * 312);
    float* t1      = take((size_t)NGRAPH * 1024);
    float* Cbuf    = take((size_t)NGRAPH * 128);
    float* f2buf   = take((size_t)NGRAPH * 512);
    int*   bsum    = (int*)take(1056);
    // drug CSR (small, dedicated)
    int*   pos_d   = (int*)take((size_t)Nd);
    int*   rowp_d  = (int*)take((size_t)Ed);
    float* coefp_d = take((size_t)Ed);
    // protein CSR lives in the dead tail of B1 (protein uses only B1[0 .. Np*80))
    size_t tail = align256((size_t)Np * 80);
    int*   pos_p   = (int*)(B1 + tail);
    int*   rowp_p  = (int*)(B1 + tail + align256((size_t)Np));
    float* coefp_p = B1 + tail + align256((size_t)Np) + align256((size_t)Ep);
    (void)ws_size;

    const int B = 256;

    // ================= drug branch (aggregate-first): 78 -> 78 -> 156 -> 312 =================
    build_csr(d_row, d_col, d_ea, Nd, Ed, dinv_d, pos_d, rowp_d, coefp_d, bsum, stream);

    // conv1: AGG(drug_x) [78] -> GEMM 78x78 + relu
    gather_agg<2,32><<<grid_for((size_t)Nd * 32), B, 0, stream>>>(
        pos_d, rowp_d, coefp_d, drug_x, dinv_d, B2, Nd, 78);
    tgemm<128,128,8,8,8,true,false><<<tgrid(Nd,78,128,128), B, 0, stream>>>(
        B2, dW1, nullptr, B1, Nd, 78, 78, 78, 0);

    // conv2: AGG(X2) [78] -> GEMM 78x156 + relu
    gather_agg<2,32><<<grid_for((size_t)Nd * 32), B, 0, stream>>>(
        pos_d, rowp_d, coefp_d, B1, dinv_d, B2, Nd, 78);
    tgemm<128,128,8,8,8,true,false><<<tgrid(Nd,156,128,128), B, 0, stream>>>(
        B2, dW2, nullptr, B1, Nd, 78, 156, 156, 0);

    // conv3: AGG(X3) [156] -> GEMM 156x312 + relu
    gather_agg<4,32><<<grid_for((size_t)Nd * 32), B, 0, stream>>>(
        pos_d, rowp_d, coefp_d, B1, dinv_d, B2, Nd, 156);
    tgemm<128,128,8,8,8,true,false><<<tgrid(Nd,312,128,128), B, 0, stream>>>(
        B2, dW3, nullptr, B1, Nd, 156, 312, 312, 0);

    pool_mean<<<NGRAPH, B, 0, stream>>>(B1, d_batch, pool, Nd, 312);

    skinny_gemm<true><<<dim3(16, NGRAPH), B, 0, stream>>>(pool, dL1_w, dL1_b, t1, 312, 1024, 1024, 0);
    skinny_gemm<true><<<dim3(1, NGRAPH), B, 0, stream>>>(t1, dL2_w, dL2_b, Cbuf, 1024, 64, 128, 0);

    // ================= protein branch (aggregate-first): 20 -> 20 -> 40 -> 80 =================
    build_csr(p_row, p_col, p_ea, Np, Ep, dinv_p, pos_p, rowp_p, coefp_p, bsum, stream);

    gather_agg<4,8><<<grid_for((size_t)Np * 8), B, 0, stream>>>(
        pos_p, rowp_p, coefp_p, prot_x, dinv_p, B2, Np, 20);
    tgemm<128,64,8,8,4,true,false><<<tgrid(Np,20,128,64), B, 0, stream>>>(
        B2, pW1, nullptr, B1, Np, 20, 20, 20, 0);

    gather_agg<4,8><<<grid_for((size_t)Np * 8), B, 0, stream>>>(
        pos_p, rowp_p, coefp_p, B1, dinv_p, B2, Np, 20);
    tgemm<128,64,8,8,4,true,false><<<tgrid(Np,40,128,64), B, 0, stream>>>(
        B2, pW2, nullptr, B1, Np, 20, 40, 40, 0);

    gather_agg<4,8><<<grid_for((size_t)Np * 8), B, 0, stream>>>(
        pos_p, rowp_p, coefp_p, B1, dinv_p, B2, Np, 40);
    tgemm<128,64,8,8,4,true,false><<<tgrid(Np,80,128,64), B, 0, stream>>>(
        B2, pW3, nullptr, B1, Np, 40, 80, 80, 0);

    pool_mean<<<NGRAPH, B, 0, stream>>>(B1, p_batch, pool, Np, 80);

    skinny_gemm<true><<<dim3(16, NGRAPH), B, 0, stream>>>(pool, pL1_w, pL1_b, t1, 80, 1024, 1024, 0);
    skinny_gemm<true><<<dim3(1, NGRAPH), B, 0, stream>>>(t1, pL2_w, pL2_b, Cbuf, 1024, 64, 128, 64);

    // ================= head: 128 -> 1024 -> 512 -> 1 =================
    skinny_gemm<true><<<dim3(16, NGRAPH), B, 0, stream>>>(Cbuf, fW1, fb1, t1, 128, 1024, 1024, 0);
    skinny_gemm<true><<<dim3(8, NGRAPH), B, 0, stream>>>(t1, fW2, fb2, f2buf, 1024, 512, 512, 0);
    final_kernel<<<grid_for((size_t)NGRAPH * 64), B, 0, stream>>>(f2buf, fW3, fb3, out, 512);
}

// Round 10
// 1978.952 us; speedup vs baseline: 5.6237x; 1.0280x over previous
//
#include <hip/hip_runtime.h>
#include <math.h>

#define NGRAPH 512

static inline unsigned grid_for(size_t n, int block = 256) {
    return (unsigned)((n + block - 1) / block);
}

__global__ void fill_i32(int* __restrict__ p, int v, size_t n) {
    size_t i = blockIdx.x * (size_t)blockDim.x + threadIdx.x;
    if (i < n) p[i] = v;
}

// histogram of destination indices
__global__ void hist_kernel(const int* __restrict__ col, int E, int* __restrict__ cnt) {
    size_t i = blockIdx.x * (size_t)blockDim.x + threadIdx.x;
    if (i < (size_t)E) atomicAdd(&cnt[col[i]], 1);
}

// dinv[n] = (cnt[n] + 1)^-0.5   (+1 = self loop)
__global__ void dinv_kernel(const int* __restrict__ cnt, float* __restrict__ d, int n) {
    size_t i = blockIdx.x * (size_t)blockDim.x + threadIdx.x;
    if (i < (size_t)n) d[i] = 1.0f / sqrtf((float)cnt[i] + 1.0f);
}

// ---- 3-pass exclusive scan over pos[] (in-place) ----
__global__ void scan_pass1(const int* __restrict__ in, int* __restrict__ bsum, int n) {
    __shared__ int sdata[256];
    int tid = threadIdx.x;
    int i = blockIdx.x * 256 + tid;
    int v = (i < n) ? in[i] : 0;
    sdata[tid] = v;
    __syncthreads();
    for (int s = 128; s > 0; s >>= 1) {
        if (tid < s) sdata[tid] += sdata[tid + s];
        __syncthreads();
    }
    if (tid == 0) bsum[blockIdx.x] = sdata[0];
}

__global__ void scan_pass2(int* __restrict__ bsum, int nb) {
    if (threadIdx.x == 0 && blockIdx.x == 0) {
        int acc = 0;
        for (int i = 0; i < nb; ++i) { int t = bsum[i]; bsum[i] = acc; acc += t; }
        bsum[nb] = acc;
    }
}

__global__ void scan_pass3(int* __restrict__ pos, const int* __restrict__ bsum, int n) {
    __shared__ int sdata[256];
    int tid = threadIdx.x;
    int i = blockIdx.x * 256 + tid;
    int v = (i < n) ? pos[i] : 0;
    sdata[tid] = v;
    __syncthreads();
    for (int ofs = 1; ofs < 256; ofs <<= 1) {
        int t = (tid >= ofs) ? sdata[tid - ofs] : 0;
        __syncthreads();
        sdata[tid] += t;
        __syncthreads();
    }
    if (i < n) pos[i] = sdata[tid] - v + bsum[blockIdx.x];
}

// CSR fill: slot = pos[col[e]]++; after this kernel pos[i] == inclusive end of node i
__global__ void csr_fill(const int* __restrict__ row, const int* __restrict__ col,
                         const float* __restrict__ attr, const float* __restrict__ dinv,
                         int* __restrict__ pos, int* __restrict__ rowp,
                         float* __restrict__ coefp, int E) {
    size_t i = blockIdx.x * (size_t)blockDim.x + threadIdx.x;
    if (i >= (size_t)E) return;
    int r = row[i], c = col[i];
    int slot = atomicAdd(&pos[c], 1);
    rowp[slot] = r;
    coefp[slot] = dinv[r] * attr[i] * dinv[c];
}

// Tiled GEMM with register prefetch + LDS double buffer (1 barrier per K-step).
// C[m][n] = act_out(A[m][:] @ W[:][n] + bias[n])
template <int BM, int BN, int BK, int TM, int TN, bool RELU_OUT, bool BIAS>
__global__ __launch_bounds__(256) void tgemm(
        const float* __restrict__ A, const float* __restrict__ W,
        const float* __restrict__ bias, float* __restrict__ C,
        int M, int K, int N, int ldc, int coff) {
    constexpr int NT = BN / TN;        // threads along n (16)
    constexpr int NJ = TN / 4;         // float4s per thread in n
    constexpr int NI = TM / 4;         // float4s per thread in m
    constexpr int LA = BM * BK / 256;  // A elements staged per thread
    constexpr int LW = BK * BN / 256;  // W elements staged per thread
    const int tid = threadIdx.x;
    const int tx = tid % NT;
    const int ty = tid / NT;
    const int m0 = blockIdx.y * BM;
    const int n0 = blockIdx.x * BN;

    __shared__ float As[2][BK][BM + 4];   // transposed A tiles
    __shared__ float Ws[2][BK][BN];

    float ra[LA], rw[LW];

    auto load_tile = [&](int k0) {
#pragma unroll
        for (int l = 0; l < LA; ++l) {
            int idx = tid + l * 256;
            int k = idx % BK, m = idx / BK;
            int gm = m0 + m, gk = k0 + k;
            ra[l] = (gm < M && gk < K) ? A[(size_t)gm * K + gk] : 0.0f;
        }
#pragma unroll
        for (int l = 0; l < LW; ++l) {
            int idx = tid + l * 256;
            int n = idx % BN, k = idx / BN;
            int gk = k0 + k, gn = n0 + n;
            rw[l] = (gk < K && gn < N) ? W[(size_t)gk * N + gn] : 0.0f;
        }
    };
    auto store_tile = [&](int buf) {
#pragma unroll
        for (int l = 0; l < LA; ++l) {
            int idx = tid + l * 256;
            As[buf][idx % BK][idx / BK] = ra[l];
        }
#pragma unroll
        for (int l = 0; l < LW; ++l) {
            int idx = tid + l * 256;
            Ws[buf][idx / BN][idx % BN] = rw[l];
        }
    };

    float acc[TM][TN];
#pragma unroll
    for (int i = 0; i < TM; ++i)
#pragma unroll
        for (int j = 0; j < TN; ++j) acc[i][j] = 0.0f;

    load_tile(0);
    store_tile(0);
    __syncthreads();
    int cur = 0;
    for (int k0 = 0; k0 < K; k0 += BK) {
        const bool has_next = (k0 + BK < K);
        if (has_next) load_tile(k0 + BK);   // global loads in flight during compute
#pragma unroll
        for (int kk = 0; kk < BK; ++kk) {
            const float4* As4 = reinterpret_cast<const float4*>(&As[cur][kk][0]);
            const float4* Ws4 = reinterpret_cast<const float4*>(&Ws[cur][kk][0]);
            float a[TM], b[TN];
#pragma unroll
            for (int ii = 0; ii < NI; ++ii)
                *reinterpret_cast<float4*>(&a[ii * 4]) = As4[ty * NI + ii];
#pragma unroll
            for (int jj = 0; jj < NJ; ++jj)
                *reinterpret_cast<float4*>(&b[jj * 4]) = Ws4[tx + NT * jj];
#pragma unroll
            for (int i = 0; i < TM; ++i)
#pragma unroll
                for (int j = 0; j < TN; ++j) acc[i][j] = fmaf(a[i], b[j], acc[i][j]);
        }
        if (has_next) {
            store_tile(cur ^ 1);
            __syncthreads();
            cur ^= 1;
        }
    }

#pragma unroll
    for (int i = 0; i < TM; ++i) {
        int gm = m0 + ty * TM + i;
        if (gm >= M) continue;
#pragma unroll
        for (int jj = 0; jj < NJ; ++jj) {
#pragma unroll
            for (int c = 0; c < 4; ++c) {
                int gn = n0 + jj * (NT * 4) + tx * 4 + c;
                if (gn >= N) continue;
                float v = acc[i][jj * 4 + c];
                if (BIAS) v += bias[gn];
                if (RELU_OUT) v = fmaxf(v, 0.0f);
                C[(size_t)gm * ldc + coff + gn] = v;
            }
        }
    }
}

template <int V> struct VT {};
template <> struct VT<2> { using T = float2; };
template <> struct VT<4> { using T = float4; };

// CSR gather-aggregate: AGG[n][:] = dinv[n]^2 * X[n][:] + sum_t coefp[t] * X[rowp[t]][:]
template <int V, int LPG>
__global__ void gather_agg(const int* __restrict__ pos, const int* __restrict__ rowp,
                           const float* __restrict__ coefp, const float* __restrict__ X,
                           const float* __restrict__ dinv, float* __restrict__ AGG,
                           int N, int F) {
    using VecT = typename VT<V>::T;
    union U { VecT v; float a[V]; };
    const int gpb = 256 / LPG;
    int gid = blockIdx.x * gpb + threadIdx.x / LPG;
    int lane = threadIdx.x % LPG;
    if (gid >= N) return;
    int start = (gid == 0) ? 0 : pos[gid - 1];
    int end = pos[gid];
    float s = dinv[gid];
    float s2 = s * s;
    for (int f = lane * V; f < F; f += LPG * V) {
        U acc;
        acc.v = *reinterpret_cast<const VecT*>(X + (size_t)gid * F + f);
#pragma unroll
        for (int j = 0; j < V; ++j) acc.a[j] *= s2;
        for (int t = start; t < end; ++t) {
            int r = rowp[t];
            float cf = coefp[t];
            U h;
            h.v = *reinterpret_cast<const VecT*>(X + (size_t)r * F + f);
#pragma unroll
            for (int j = 0; j < V; ++j) acc.a[j] = fmaf(cf, h.a[j], acc.a[j]);
        }
        *reinterpret_cast<VecT*>(AGG + (size_t)gid * F + f) = acc.v;
    }
}

// segment mean-pool over sorted batch: out[g][f] = mean over nodes of relu(X[n][f])
__global__ void pool_mean(const float* __restrict__ X, const int* __restrict__ batch,
                          float* __restrict__ out, int N, int F) {
    int g = blockIdx.x;
    int lo = 0, hi = N;
    while (lo < hi) { int mid = (lo + hi) >> 1; if (batch[mid] < g) lo = mid + 1; else hi = mid; }
    int s0 = lo;
    hi = N;
    while (lo < hi) { int mid = (lo + hi) >> 1; if (batch[mid] < g + 1) lo = mid + 1; else hi = mid; }
    int s1 = lo;
    int c = s1 - s0;
    float inv = 1.0f / (float)(c > 0 ? c : 1);
    for (int f = threadIdx.x; f < F; f += blockDim.x) {
        float acc = 0.0f;
        for (int n = s0; n < s1; ++n) acc += fmaxf(X[(size_t)n * F + f], 0.0f);
        out[(size_t)g * F + f] = acc * inv;
    }
}

// Skinny MLP GEMM: one block per (graph g, 64-wide m-chunk).
template <bool RELU_OUT>
__global__ __launch_bounds__(256) void skinny_gemm(
        const float* __restrict__ A, const float* __restrict__ W,
        const float* __restrict__ bias, float* __restrict__ C,
        int K, int M, int ldc, int coff) {
    __shared__ float As[1024];          // K <= 1024
    __shared__ float red[4][64];
    const int tid = threadIdx.x;
    const int m_l = tid & 63;
    const int q = tid >> 6;
    const int g = blockIdx.y;
    const int m0 = blockIdx.x * 64;

    for (int idx = tid; idx < K; idx += 256) As[idx] = A[(size_t)g * K + idx];
    __syncthreads();

    const int Kq = (K + 3) >> 2;
    const int ks = q * Kq;
    const int ke = (ks + Kq < K) ? ks + Kq : K;
    const int m = m0 + m_l;
    float acc = 0.0f;
    if (m < M) {
        for (int k = ks; k < ke; ++k) acc = fmaf(As[k], W[(size_t)k * M + m], acc);
    }
    red[q][m_l] = acc;
    __syncthreads();
    if (q == 0 && m < M) {
        float v = red[0][m_l] + red[1][m_l] + red[2][m_l] + red[3][m_l] + bias[m];
        if (RELU_OUT) v = fmaxf(v, 0.0f);
        C[(size_t)g * ldc + coff + m] = v;
    }
}

// final: out[g] = A[g][:K] . w + b[0], one wave per graph
__global__ void final_kernel(const float* __restrict__ A, const float* __restrict__ w,
                             const float* __restrict__ b, float* __restrict__ out, int K) {
    int wave = (blockIdx.x * blockDim.x + threadIdx.x) >> 6;
    int lane = threadIdx.x & 63;
    if (wave >= NGRAPH) return;
    const float* ar = A + (size_t)wave * K;
    float acc = 0.0f;
    for (int k = lane; k < K; k += 64) acc = fmaf(ar[k], w[k], acc);
#pragma unroll
    for (int s = 32; s > 0; s >>= 1) acc += __shfl_down(acc, s, 64);
    if (lane == 0) out[wave] = acc + b[0];
}

static inline dim3 tgrid(int M, int N, int BM, int BN) {
    return dim3((unsigned)((N + BN - 1) / BN), (unsigned)((M + BM - 1) / BM));
}

// build CSR for one graph (stream-ordered); pos ends as inclusive-end array
static void build_csr(const int* row, const int* col, const float* attr,
                      int N, int E, float* dinv, int* pos,
                      int* rowp, float* coefp, int* bsum, hipStream_t stream) {
    const int B = 256;
    int nb = (N + 255) / 256;
    fill_i32<<<grid_for(N), B, 0, stream>>>(pos, 0, (size_t)N);
    hist_kernel<<<grid_for(E), B, 0, stream>>>(col, E, pos);
    dinv_kernel<<<grid_for(N), B, 0, stream>>>(pos, dinv, N);
    scan_pass1<<<nb, B, 0, stream>>>(pos, bsum, N);
    scan_pass2<<<1, 64, 0, stream>>>(bsum, nb);
    scan_pass3<<<nb, B, 0, stream>>>(pos, bsum, N);
    csr_fill<<<grid_for(E), B, 0, stream>>>(row, col, attr, dinv, pos, rowp, coefp, E);
}

extern "C" void kernel_launch(void* const* d_in, const int* in_sizes, int n_in,
                              void* d_out, int out_size, void* d_ws, size_t ws_size,
                              hipStream_t stream) {
    const float* drug_x  = (const float*)d_in[0];
    const int*   d_ei    = (const int*)d_in[1];
    const float* d_ea    = (const float*)d_in[2];
    const int*   d_batch = (const int*)d_in[3];
    const float* prot_x  = (const float*)d_in[4];
    const int*   p_ei    = (const int*)d_in[5];
    const float* p_ea    = (const float*)d_in[6];
    const int*   p_batch = (const int*)d_in[7];
    const float* dW1 = (const float*)d_in[8];
    const float* dW2 = (const float*)d_in[9];
    const float* dW3 = (const float*)d_in[10];
    const float* dL1_w = (const float*)d_in[11];
    const float* dL1_b = (const float*)d_in[12];
    const float* dL2_w = (const float*)d_in[13];
    const float* dL2_b = (const float*)d_in[14];
    const float* pW1 = (const float*)d_in[15];
    const float* pW2 = (const float*)d_in[16];
    const float* pW3 = (const float*)d_in[17];
    const float* pL1_w = (const float*)d_in[18];
    const float* pL1_b = (const float*)d_in[19];
    const float* pL2_w = (const float*)d_in[20];
    const float* pL2_b = (const float*)d_in[21];
    const float* fW1 = (const float*)d_in[22];
    const float* fb1 = (const float*)d_in[23];
    const float* fW2 = (const float*)d_in[24];
    const float* fb2 = (const float*)d_in[25];
    const float* fW3 = (const float*)d_in[26];
    const float* fb3 = (const float*)d_in[27];
    float* out = (float*)d_out;

    const int Nd = in_sizes[0] / 78;
    const int Ed = in_sizes[1] / 2;
    const int Np = in_sizes[4] / 20;
    const int Ep = in_sizes[5] / 2;
    const int* d_row = d_ei;
    const int* d_col = d_ei + Ed;
    const int* p_row = p_ei;
    const int* p_col = p_ei + Ep;

    // ---- workspace layout (floats); proven-safe total ----
    float* ws = (float*)d_ws;
    size_t off = 0;
    auto align256 = [](size_t n) -> size_t { return (n + 255) & ~(size_t)255; };
    auto take = [&](size_t n) -> float* {
        float* p = ws + off;
        off += align256(n);
        return p;
    };
    float* B1      = take((size_t)Nd * 312);   // GEMM output H / conv outputs
    float* B2      = take((size_t)Nd * 312);   // aggregate output
    float* dinv_d  = take((size_t)Nd);
    float* dinv_p  = take((size_t)Np);
    float* pool    = take((size_t)NGRAPH * 312);
    float* t1      = take((size_t)NGRAPH * 1024);
    float* Cbuf    = take((size_t)NGRAPH * 128);
    float* f2buf   = take((size_t)NGRAPH * 512);
    int*   bsum    = (int*)take(1056);
    // drug CSR (small, dedicated)
    int*   pos_d   = (int*)take((size_t)Nd);
    int*   rowp_d  = (int*)take((size_t)Ed);
    float* coefp_d = take((size_t)Ed);
    // protein CSR lives in the dead tail of B1 (protein uses only B1[0 .. Np*80))
    size_t tail = align256((size_t)Np * 80);
    int*   pos_p   = (int*)(B1 + tail);
    int*   rowp_p  = (int*)(B1 + tail + align256((size_t)Np));
    float* coefp_p = B1 + tail + align256((size_t)Np) + align256((size_t)Ep);
    (void)ws_size;

    const int B = 256;

    // ================= drug branch (aggregate-first): 78 -> 78 -> 156 -> 312 =================
    build_csr(d_row, d_col, d_ea, Nd, Ed, dinv_d, pos_d, rowp_d, coefp_d, bsum, stream);

    // conv1: AGG(drug_x) [78] -> GEMM 78x78 + relu
    gather_agg<2,32><<<grid_for((size_t)Nd * 32), B, 0, stream>>>(
        pos_d, rowp_d, coefp_d, drug_x, dinv_d, B2, Nd, 78);
    tgemm<128,128,8,8,8,true,false><<<tgrid(Nd,78,128,128), B, 0, stream>>>(
        B2, dW1, nullptr, B1, Nd, 78, 78, 78, 0);

    // conv2: AGG(X2) [78] -> GEMM 78x156 + relu
    gather_agg<2,32><<<grid_for((size_t)Nd * 32), B, 0, stream>>>(
        pos_d, rowp_d, coefp_d, B1, dinv_d, B2, Nd, 78);
    tgemm<128,128,8,8,8,true,false><<<tgrid(Nd,156,128,128), B, 0, stream>>>(
        B2, dW2, nullptr, B1, Nd, 78, 156, 156, 0);

    // conv3: AGG(X3) [156] -> GEMM 156x312 + relu
    gather_agg<4,32><<<grid_for((size_t)Nd * 32), B, 0, stream>>>(
        pos_d, rowp_d, coefp_d, B1, dinv_d, B2, Nd, 156);
    tgemm<128,128,8,8,8,true,false><<<tgrid(Nd,312,128,128), B, 0, stream>>>(
        B2, dW3, nullptr, B1, Nd, 156, 312, 312, 0);

    pool_mean<<<NGRAPH, B, 0, stream>>>(B1, d_batch, pool, Nd, 312);

    skinny_gemm<true><<<dim3(16, NGRAPH), B, 0, stream>>>(pool, dL1_w, dL1_b, t1, 312, 1024, 1024, 0);
    skinny_gemm<true><<<dim3(1, NGRAPH), B, 0, stream>>>(t1, dL2_w, dL2_b, Cbuf, 1024, 64, 128, 0);

    // ================= protein branch (aggregate-first): 20 -> 20 -> 40 -> 80 =================
    build_csr(p_row, p_col, p_ea, Np, Ep, dinv_p, pos_p, rowp_p, coefp_p, bsum, stream);

    gather_agg<4,8><<<grid_for((size_t)Np * 8), B, 0, stream>>>(
        pos_p, rowp_p, coefp_p, prot_x, dinv_p, B2, Np, 20);
    tgemm<128,64,8,8,4,true,false><<<tgrid(Np,20,128,64), B, 0, stream>>>(
        B2, pW1, nullptr, B1, Np, 20, 20, 20, 0);

    gather_agg<4,8><<<grid_for((size_t)Np * 8), B, 0, stream>>>(
        pos_p, rowp_p, coefp_p, B1, dinv_p, B2, Np, 20);
    tgemm<128,64,8,8,4,true,false><<<tgrid(Np,40,128,64), B, 0, stream>>>(
        B2, pW2, nullptr, B1, Np, 20, 40, 40, 0);

    gather_agg<4,8><<<grid_for((size_t)Np * 8), B, 0, stream>>>(
        pos_p, rowp_p, coefp_p, B1, dinv_p, B2, Np, 40);
    tgemm<128,64,8,8,4,true,false><<<tgrid(Np,80,128,64), B, 0, stream>>>(
        B2, pW3, nullptr, B1, Np, 40, 80, 80, 0);

    pool_mean<<<NGRAPH, B, 0, stream>>>(B1, p_batch, pool, Np, 80);

    skinny_gemm<true><<<dim3(16, NGRAPH), B, 0, stream>>>(pool, pL1_w, pL1_b, t1, 80, 1024, 1024, 0);
    skinny_gemm<true><<<dim3(1, NGRAPH), B, 0, stream>>>(t1, pL2_w, pL2_b, Cbuf, 1024, 64, 128, 64);

    // ================= head: 128 -> 1024 -> 512 -> 1 =================
    skinny_gemm<true><<<dim3(16, NGRAPH), B, 0, stream>>>(Cbuf, fW1, fb1, t1, 128, 1024, 1024, 0);
    skinny_gemm<true><<<dim3(8, NGRAPH), B, 0, stream>>>(t1, fW2, fb2, f2buf, 1024, 512, 512, 0);
    final_kernel<<<grid_for((size_t)NGRAPH * 64), B, 0, stream>>>(f2buf, fW3, fb3, out, 512);
}

// Round 11
// 1894.224 us; speedup vs baseline: 5.8753x; 1.0447x over previous
//
#include <hip/hip_runtime.h>
#include <math.h>

#define NGRAPH 512

static inline unsigned grid_for(size_t n, int block = 256) {
    return (unsigned)((n + block - 1) / block);
}

__global__ void fill_i32(int* __restrict__ p, int v, size_t n) {
    size_t i = blockIdx.x * (size_t)blockDim.x + threadIdx.x;
    if (i < n) p[i] = v;
}

__global__ void hist_kernel(const int* __restrict__ col, int E, int* __restrict__ cnt) {
    size_t i = blockIdx.x * (size_t)blockDim.x + threadIdx.x;
    if (i < (size_t)E) atomicAdd(&cnt[col[i]], 1);
}

// dinv[n] = (cnt[n] + 1)^-0.5   (+1 = self loop)
__global__ void dinv_kernel(const int* __restrict__ cnt, float* __restrict__ d, int n) {
    size_t i = blockIdx.x * (size_t)blockDim.x + threadIdx.x;
    if (i < (size_t)n) d[i] = 1.0f / sqrtf((float)cnt[i] + 1.0f);
}

// ---- 3-pass exclusive scan over pos[] (in-place) ----
__global__ void scan_pass1(const int* __restrict__ in, int* __restrict__ bsum, int n) {
    __shared__ int sdata[256];
    int tid = threadIdx.x;
    int i = blockIdx.x * 256 + tid;
    int v = (i < n) ? in[i] : 0;
    sdata[tid] = v;
    __syncthreads();
    for (int s = 128; s > 0; s >>= 1) {
        if (tid < s) sdata[tid] += sdata[tid + s];
        __syncthreads();
    }
    if (tid == 0) bsum[blockIdx.x] = sdata[0];
}

__global__ void scan_pass2(int* __restrict__ bsum, int nb) {
    if (threadIdx.x == 0 && blockIdx.x == 0) {
        int acc = 0;
        for (int i = 0; i < nb; ++i) { int t = bsum[i]; bsum[i] = acc; acc += t; }
        bsum[nb] = acc;
    }
}

__global__ void scan_pass3(int* __restrict__ pos, const int* __restrict__ bsum, int n) {
    __shared__ int sdata[256];
    int tid = threadIdx.x;
    int i = blockIdx.x * 256 + tid;
    int v = (i < n) ? pos[i] : 0;
    sdata[tid] = v;
    __syncthreads();
    for (int ofs = 1; ofs < 256; ofs <<= 1) {
        int t = (tid >= ofs) ? sdata[tid - ofs] : 0;
        __syncthreads();
        sdata[tid] += t;
        __syncthreads();
    }
    if (i < n) pos[i] = sdata[tid] - v + bsum[blockIdx.x];
}

// CSR fill: slot = pos[col[e]]++; after this kernel pos[i] == inclusive end of node i
__global__ void csr_fill(const int* __restrict__ row, const int* __restrict__ col,
                         const float* __restrict__ attr, const float* __restrict__ dinv,
                         int* __restrict__ pos, int* __restrict__ rowp,
                         float* __restrict__ coefp, int E) {
    size_t i = blockIdx.x * (size_t)blockDim.x + threadIdx.x;
    if (i >= (size_t)E) return;
    int r = row[i], c = col[i];
    int slot = atomicAdd(&pos[c], 1);
    rowp[slot] = r;
    coefp[slot] = dinv[r] * attr[i] * dinv[c];
}

// Tiled GEMM with register prefetch + LDS double buffer (1 barrier per K-step).
template <int BM, int BN, int BK, int TM, int TN, bool RELU_OUT, bool BIAS>
__global__ __launch_bounds__(256) void tgemm(
        const float* __restrict__ A, const float* __restrict__ W,
        const float* __restrict__ bias, float* __restrict__ C,
        int M, int K, int N, int ldc, int coff) {
    constexpr int NT = BN / TN;
    constexpr int NJ = TN / 4;
    constexpr int NI = TM / 4;
    constexpr int LA = BM * BK / 256;
    constexpr int LW = BK * BN / 256;
    const int tid = threadIdx.x;
    const int tx = tid % NT;
    const int ty = tid / NT;
    const int m0 = blockIdx.y * BM;
    const int n0 = blockIdx.x * BN;

    __shared__ float As[2][BK][BM + 4];
    __shared__ float Ws[2][BK][BN];

    float ra[LA], rw[LW];

    auto load_tile = [&](int k0) {
#pragma unroll
        for (int l = 0; l < LA; ++l) {
            int idx = tid + l * 256;
            int k = idx % BK, m = idx / BK;
            int gm = m0 + m, gk = k0 + k;
            ra[l] = (gm < M && gk < K) ? A[(size_t)gm * K + gk] : 0.0f;
        }
#pragma unroll
        for (int l = 0; l < LW; ++l) {
            int idx = tid + l * 256;
            int n = idx % BN, k = idx / BN;
            int gk = k0 + k, gn = n0 + n;
            rw[l] = (gk < K && gn < N) ? W[(size_t)gk * N + gn] : 0.0f;
        }
    };
    auto store_tile = [&](int buf) {
#pragma unroll
        for (int l = 0; l < LA; ++l) {
            int idx = tid + l * 256;
            As[buf][idx % BK][idx / BK] = ra[l];
        }
#pragma unroll
        for (int l = 0; l < LW; ++l) {
            int idx = tid + l * 256;
            Ws[buf][idx / BN][idx % BN] = rw[l];
        }
    };

    float acc[TM][TN];
#pragma unroll
    for (int i = 0; i < TM; ++i)
#pragma unroll
        for (int j = 0; j < TN; ++j) acc[i][j] = 0.0f;

    load_tile(0);
    store_tile(0);
    __syncthreads();
    int cur = 0;
    for (int k0 = 0; k0 < K; k0 += BK) {
        const bool has_next = (k0 + BK < K);
        if (has_next) load_tile(k0 + BK);
#pragma unroll
        for (int kk = 0; kk < BK; ++kk) {
            const float4* As4 = reinterpret_cast<const float4*>(&As[cur][kk][0]);
            const float4* Ws4 = reinterpret_cast<const float4*>(&Ws[cur][kk][0]);
            float a[TM], b[TN];
#pragma unroll
            for (int ii = 0; ii < NI; ++ii)
                *reinterpret_cast<float4*>(&a[ii * 4]) = As4[ty * NI + ii];
#pragma unroll
            for (int jj = 0; jj < NJ; ++jj)
                *reinterpret_cast<float4*>(&b[jj * 4]) = Ws4[tx + NT * jj];
#pragma unroll
            for (int i = 0; i < TM; ++i)
#pragma unroll
                for (int j = 0; j < TN; ++j) acc[i][j] = fmaf(a[i], b[j], acc[i][j]);
        }
        if (has_next) {
            store_tile(cur ^ 1);
            __syncthreads();
            cur ^= 1;
        }
    }

#pragma unroll
    for (int i = 0; i < TM; ++i) {
        int gm = m0 + ty * TM + i;
        if (gm >= M) continue;
#pragma unroll
        for (int jj = 0; jj < NJ; ++jj) {
#pragma unroll
            for (int c = 0; c < 4; ++c) {
                int gn = n0 + jj * (NT * 4) + tx * 4 + c;
                if (gn >= N) continue;
                float v = acc[i][jj * 4 + c];
                if (BIAS) v += bias[gn];
                if (RELU_OUT) v = fmaxf(v, 0.0f);
                C[(size_t)gm * ldc + coff + gn] = v;
            }
        }
    }
}

template <int V> struct VT {};
template <> struct VT<2> { using T = float2; };
template <> struct VT<4> { using T = float4; };

// CSR gather-aggregate with 4x edge unroll (4 independent row loads in flight):
// AGG[n][:] = dinv[n]^2 * X[n][:] + sum_t coefp[t] * X[rowp[t]][:]
template <int V, int LPG>
__global__ void gather_agg(const int* __restrict__ pos, const int* __restrict__ rowp,
                           const float* __restrict__ coefp, const float* __restrict__ X,
                           const float* __restrict__ dinv, float* __restrict__ AGG,
                           int N, int F) {
    using VecT = typename VT<V>::T;
    union U { VecT v; float a[V]; };
    const int gpb = 256 / LPG;
    int gid = blockIdx.x * gpb + threadIdx.x / LPG;
    int lane = threadIdx.x % LPG;
    if (gid >= N) return;
    int start = (gid == 0) ? 0 : pos[gid - 1];
    int end = pos[gid];
    float s = dinv[gid];
    float s2 = s * s;
    for (int f = lane * V; f < F; f += LPG * V) {
        U acc;
        acc.v = *reinterpret_cast<const VecT*>(X + (size_t)gid * F + f);
#pragma unroll
        for (int j = 0; j < V; ++j) acc.a[j] *= s2;
        int t = start;
        for (; t + 4 <= end; t += 4) {
            int r0 = rowp[t], r1 = rowp[t + 1], r2 = rowp[t + 2], r3 = rowp[t + 3];
            float c0 = coefp[t], c1 = coefp[t + 1], c2 = coefp[t + 2], c3 = coefp[t + 3];
            U h0, h1, h2, h3;
            h0.v = *reinterpret_cast<const VecT*>(X + (size_t)r0 * F + f);
            h1.v = *reinterpret_cast<const VecT*>(X + (size_t)r1 * F + f);
            h2.v = *reinterpret_cast<const VecT*>(X + (size_t)r2 * F + f);
            h3.v = *reinterpret_cast<const VecT*>(X + (size_t)r3 * F + f);
#pragma unroll
            for (int j = 0; j < V; ++j) {
                float v = fmaf(c0, h0.a[j], acc.a[j]);
                v = fmaf(c1, h1.a[j], v);
                v = fmaf(c2, h2.a[j], v);
                acc.a[j] = fmaf(c3, h3.a[j], v);
            }
        }
        for (; t < end; ++t) {
            int r = rowp[t];
            float cf = coefp[t];
            U h;
            h.v = *reinterpret_cast<const VecT*>(X + (size_t)r * F + f);
#pragma unroll
            for (int j = 0; j < V; ++j) acc.a[j] = fmaf(cf, h.a[j], acc.a[j]);
        }
        *reinterpret_cast<VecT*>(AGG + (size_t)gid * F + f) = acc.v;
    }
}

// striped mean-pool for F < 256: threads = (f, stripe), S = 256/F stripes, LDS reduce
__global__ void pool_mean_s(const float* __restrict__ X, const int* __restrict__ batch,
                            float* __restrict__ out, int N, int F, int S) {
    __shared__ float red[256];
    int g = blockIdx.x;
    int lo = 0, hi = N;
    while (lo < hi) { int mid = (lo + hi) >> 1; if (batch[mid] < g) lo = mid + 1; else hi = mid; }
    int s0 = lo;
    hi = N;
    while (lo < hi) { int mid = (lo + hi) >> 1; if (batch[mid] < g + 1) lo = mid + 1; else hi = mid; }
    int s1 = lo;
    int c = s1 - s0;
    float inv = 1.0f / (float)(c > 0 ? c : 1);
    int t = threadIdx.x;
    int stripe = t / F;
    int f = t - stripe * F;
    float acc = 0.0f;
    if (stripe < S) {
        for (int n = s0 + stripe; n < s1; n += S)
            acc += fmaxf(X[(size_t)n * F + f], 0.0f);
    }
    red[t] = acc;
    __syncthreads();
    if (t < F) {
        float v = red[t];
        for (int s = 1; s < S; ++s) v += red[t + s * F];
        out[(size_t)g * F + t] = v * inv;
    }
}

// mean-pool for F >= 256 (thread strides f, serial over nodes)
__global__ void pool_mean(const float* __restrict__ X, const int* __restrict__ batch,
                          float* __restrict__ out, int N, int F) {
    int g = blockIdx.x;
    int lo = 0, hi = N;
    while (lo < hi) { int mid = (lo + hi) >> 1; if (batch[mid] < g) lo = mid + 1; else hi = mid; }
    int s0 = lo;
    hi = N;
    while (lo < hi) { int mid = (lo + hi) >> 1; if (batch[mid] < g + 1) lo = mid + 1; else hi = mid; }
    int s1 = lo;
    int c = s1 - s0;
    float inv = 1.0f / (float)(c > 0 ? c : 1);
    for (int f = threadIdx.x; f < F; f += blockDim.x) {
        float acc = 0.0f;
        for (int n = s0; n < s1; ++n) acc += fmaxf(X[(size_t)n * F + f], 0.0f);
        out[(size_t)g * F + f] = acc * inv;
    }
}

// Skinny MLP GEMM: one block per (graph g, 64-wide m-chunk).
template <bool RELU_OUT>
__global__ __launch_bounds__(256) void skinny_gemm(
        const float* __restrict__ A, const float* __restrict__ W,
        const float* __restrict__ bias, float* __restrict__ C,
        int K, int M, int ldc, int coff) {
    __shared__ float As[1024];
    __shared__ float red[4][64];
    const int tid = threadIdx.x;
    const int m_l = tid & 63;
    const int q = tid >> 6;
    const int g = blockIdx.y;
    const int m0 = blockIdx.x * 64;

    for (int idx = tid; idx < K; idx += 256) As[idx] = A[(size_t)g * K + idx];
    __syncthreads();

    const int Kq = (K + 3) >> 2;
    const int ks = q * Kq;
    const int ke = (ks + Kq < K) ? ks + Kq : K;
    const int m = m0 + m_l;
    float acc = 0.0f;
    if (m < M) {
        for (int k = ks; k < ke; ++k) acc = fmaf(As[k], W[(size_t)k * M + m], acc);
    }
    red[q][m_l] = acc;
    __syncthreads();
    if (q == 0 && m < M) {
        float v = red[0][m_l] + red[1][m_l] + red[2][m_l] + red[3][m_l] + bias[m];
        if (RELU_OUT) v = fmaxf(v, 0.0f);
        C[(size_t)g * ldc + coff + m] = v;
    }
}

// final: out[g] = A[g][:K] . w + b[0], one wave per graph
__global__ void final_kernel(const float* __restrict__ A, const float* __restrict__ w,
                             const float* __restrict__ b, float* __restrict__ out, int K) {
    int wave = (blockIdx.x * blockDim.x + threadIdx.x) >> 6;
    int lane = threadIdx.x & 63;
    if (wave >= NGRAPH) return;
    const float* ar = A + (size_t)wave * K;
    float acc = 0.0f;
    for (int k = lane; k < K; k += 64) acc = fmaf(ar[k], w[k], acc);
#pragma unroll
    for (int s = 32; s > 0; s >>= 1) acc += __shfl_down(acc, s, 64);
    if (lane == 0) out[wave] = acc + b[0];
}

static inline dim3 tgrid(int M, int N, int BM, int BN) {
    return dim3((unsigned)((N + BN - 1) / BN), (unsigned)((M + BM - 1) / BM));
}

// build CSR for one graph (stream-ordered); pos ends as inclusive-end array
static void build_csr(const int* row, const int* col, const float* attr,
                      int N, int E, float* dinv, int* pos,
                      int* rowp, float* coefp, int* bsum, hipStream_t stream) {
    const int B = 256;
    int nb = (N + 255) / 256;
    fill_i32<<<grid_for(N), B, 0, stream>>>(pos, 0, (size_t)N);
    hist_kernel<<<grid_for(E), B, 0, stream>>>(col, E, pos);
    dinv_kernel<<<grid_for(N), B, 0, stream>>>(pos, dinv, N);
    scan_pass1<<<nb, B, 0, stream>>>(pos, bsum, N);
    scan_pass2<<<1, 64, 0, stream>>>(bsum, nb);
    scan_pass3<<<nb, B, 0, stream>>>(pos, bsum, N);
    csr_fill<<<grid_for(E), B, 0, stream>>>(row, col, attr, dinv, pos, rowp, coefp, E);
}

extern "C" void kernel_launch(void* const* d_in, const int* in_sizes, int n_in,
                              void* d_out, int out_size, void* d_ws, size_t ws_size,
                              hipStream_t stream) {
    const float* drug_x  = (const float*)d_in[0];
    const int*   d_ei    = (const int*)d_in[1];
    const float* d_ea    = (const float*)d_in[2];
    const int*   d_batch = (const int*)d_in[3];
    const float* prot_x  = (const float*)d_in[4];
    const int*   p_ei    = (const int*)d_in[5];
    const float* p_ea    = (const float*)d_in[6];
    const int*   p_batch = (const int*)d_in[7];
    const float* dW1 = (const float*)d_in[8];
    const float* dW2 = (const float*)d_in[9];
    const float* dW3 = (const float*)d_in[10];
    const float* dL1_w = (const float*)d_in[11];
    const float* dL1_b = (const float*)d_in[12];
    const float* dL2_w = (const float*)d_in[13];
    const float* dL2_b = (const float*)d_in[14];
    const float* pW1 = (const float*)d_in[15];
    const float* pW2 = (const float*)d_in[16];
    const float* pW3 = (const float*)d_in[17];
    const float* pL1_w = (const float*)d_in[18];
    const float* pL1_b = (const float*)d_in[19];
    const float* pL2_w = (const float*)d_in[20];
    const float* pL2_b = (const float*)d_in[21];
    const float* fW1 = (const float*)d_in[22];
    const float* fb1 = (const float*)d_in[23];
    const float* fW2 = (const float*)d_in[24];
    const float* fb2 = (const float*)d_in[25];
    const float* fW3 = (const float*)d_in[26];
    const float* fb3 = (const float*)d_in[27];
    float* out = (float*)d_out;

    const int Nd = in_sizes[0] / 78;
    const int Ed = in_sizes[1] / 2;
    const int Np = in_sizes[4] / 20;
    const int Ep = in_sizes[5] / 2;
    const int* d_row = d_ei;
    const int* d_col = d_ei + Ed;
    const int* p_row = p_ei;
    const int* p_col = p_ei + Ep;

    // ---- workspace layout (floats); proven-safe total ----
    float* ws = (float*)d_ws;
    size_t off = 0;
    auto align256 = [](size_t n) -> size_t { return (n + 255) & ~(size_t)255; };
    auto take = [&](size_t n) -> float* {
        float* p = ws + off;
        off += align256(n);
        return p;
    };
    float* B1      = take((size_t)Nd * 312);   // GEMM output H / conv outputs
    float* B2      = take((size_t)Nd * 312);   // aggregate output
    float* dinv_d  = take((size_t)Nd);
    float* dinv_p  = take((size_t)Np);
    float* pool    = take((size_t)NGRAPH * 312);
    float* t1      = take((size_t)NGRAPH * 1024);
    float* Cbuf    = take((size_t)NGRAPH * 128);
    float* f2buf   = take((size_t)NGRAPH * 512);
    int*   bsum    = (int*)take(1056);
    // drug CSR (small, dedicated)
    int*   pos_d   = (int*)take((size_t)Nd);
    int*   rowp_d  = (int*)take((size_t)Ed);
    float* coefp_d = take((size_t)Ed);
    // protein CSR lives in the dead tail of B1 (protein uses only B1[0 .. Np*80))
    size_t tail = align256((size_t)Np * 80);
    int*   pos_p   = (int*)(B1 + tail);
    int*   rowp_p  = (int*)(B1 + tail + align256((size_t)Np));
    float* coefp_p = B1 + tail + align256((size_t)Np) + align256((size_t)Ep);
    (void)ws_size;

    const int B = 256;

    // ================= drug branch (aggregate-first): 78 -> 78 -> 156 -> 312 =================
    build_csr(d_row, d_col, d_ea, Nd, Ed, dinv_d, pos_d, rowp_d, coefp_d, bsum, stream);

    gather_agg<2,32><<<grid_for((size_t)Nd * 32), B, 0, stream>>>(
        pos_d, rowp_d, coefp_d, drug_x, dinv_d, B2, Nd, 78);
    tgemm<128,128,8,8,8,true,false><<<tgrid(Nd,78,128,128), B, 0, stream>>>(
        B2, dW1, nullptr, B1, Nd, 78, 78, 78, 0);

    gather_agg<2,32><<<grid_for((size_t)Nd * 32), B, 0, stream>>>(
        pos_d, rowp_d, coefp_d, B1, dinv_d, B2, Nd, 78);
    tgemm<128,128,8,8,8,true,false><<<tgrid(Nd,156,128,128), B, 0, stream>>>(
        B2, dW2, nullptr, B1, Nd, 78, 156, 156, 0);

    gather_agg<4,32><<<grid_for((size_t)Nd * 32), B, 0, stream>>>(
        pos_d, rowp_d, coefp_d, B1, dinv_d, B2, Nd, 156);
    tgemm<128,128,8,8,8,true,false><<<tgrid(Nd,312,128,128), B, 0, stream>>>(
        B2, dW3, nullptr, B1, Nd, 156, 312, 312, 0);

    pool_mean<<<NGRAPH, B, 0, stream>>>(B1, d_batch, pool, Nd, 312);

    skinny_gemm<true><<<dim3(16, NGRAPH), B, 0, stream>>>(pool, dL1_w, dL1_b, t1, 312, 1024, 1024, 0);
    skinny_gemm<true><<<dim3(1, NGRAPH), B, 0, stream>>>(t1, dL2_w, dL2_b, Cbuf, 1024, 64, 128, 0);

    // ================= protein branch (aggregate-first): 20 -> 20 -> 40 -> 80 =================
    build_csr(p_row, p_col, p_ea, Np, Ep, dinv_p, pos_p, rowp_p, coefp_p, bsum, stream);

    gather_agg<4,4><<<grid_for((size_t)Np * 4), B, 0, stream>>>(
        pos_p, rowp_p, coefp_p, prot_x, dinv_p, B2, Np, 20);
    tgemm<128,64,8,8,4,true,false><<<tgrid(Np,20,128,64), B, 0, stream>>>(
        B2, pW1, nullptr, B1, Np, 20, 20, 20, 0);

    gather_agg<4,4><<<grid_for((size_t)Np * 4), B, 0, stream>>>(
        pos_p, rowp_p, coefp_p, B1, dinv_p, B2, Np, 20);
    tgemm<128,64,8,8,4,true,false><<<tgrid(Np,40,128,64), B, 0, stream>>>(
        B2, pW2, nullptr, B1, Np, 20, 40, 40, 0);

    gather_agg<4,8><<<grid_for((size_t)Np * 8), B, 0, stream>>>(
        pos_p, rowp_p, coefp_p, B1, dinv_p, B2, Np, 40);
    tgemm<128,64,8,8,4,true,false><<<tgrid(Np,80,128,64), B, 0, stream>>>(
        B2, pW3, nullptr, B1, Np, 40, 80, 80, 0);

    pool_mean_s<<<NGRAPH, B, 0, stream>>>(B1, p_batch, pool, Np, 80, 3);

    skinny_gemm<true><<<dim3(16, NGRAPH), B, 0, stream>>>(pool, pL1_w, pL1_b, t1, 80, 1024, 1024, 0);
    skinny_gemm<true><<<dim3(1, NGRAPH), B, 0, stream>>>(t1, pL2_w, pL2_b, Cbuf, 1024, 64, 128, 64);

    // ================= head: 128 -> 1024 -> 512 -> 1 =================
    skinny_gemm<true><<<dim3(16, NGRAPH), B, 0, stream>>>(Cbuf, fW1, fb1, t1, 128, 1024, 1024, 0);
    skinny_gemm<true><<<dim3(8, NGRAPH), B, 0, stream>>>(t1, fW2, fb2, f2buf, 1024, 512, 512, 0);
    final_kernel<<<grid_for((size_t)NGRAPH * 64), B, 0, stream>>>(f2buf, fW3, fb3, out, 512);
}